// Round 1
// baseline (1069.864 us; speedup 1.0000x reference)
//
#include <hip/hip_runtime.h>
#include <math.h>

namespace {

constexpr int B_  = 2;
constexpr int S_  = 2048;
constexpr int D_  = 1024;
constexpr int H_  = 16;
constexpr int DK_ = 64;

// ---------------------------------------------------------------------------
// K1: fused QKV projection + RoPE.
// grid = (B*S/64, H, 3[q,k,v]), block = 256.
// C tile [64 s x 64 k] = X[b, s0:s0+64, :] @ W[h]  (D=1024 inner dim)
// ---------------------------------------------------------------------------
__global__ __launch_bounds__(256)
void qkv_rope_kernel(const float* __restrict__ x,
                     const float* __restrict__ Wq,
                     const float* __restrict__ Wk,
                     const float* __restrict__ Wv,
                     float* __restrict__ Q,
                     float* __restrict__ K,
                     float* __restrict__ V)
{
    constexpr int TS = 64, BK = 32;
    const int tilesPerB = S_ / TS;                  // 32
    const int b   = blockIdx.x / tilesPerB;
    const int s0  = (blockIdx.x % tilesPerB) * TS;
    const int h   = blockIdx.y;
    const int sel = blockIdx.z;

    const float* W = (sel == 0 ? Wq : (sel == 1 ? Wk : Wv)) + (size_t)h * D_ * DK_;
    float* dst     = (sel == 0 ? Q  : (sel == 1 ? K  : V));

    __shared__ float Xs[TS][36];    // stride 36: 16B-aligned float4 stores, banks spread
    __shared__ float Ws[BK][TS];

    const int tid = threadIdx.x;
    const int ty  = tid >> 4;       // 0..15
    const int tx  = tid & 15;       // 0..15

    float acc[4][4] = {};

    const float* xb = x + ((size_t)b * S_ + s0) * D_;

    for (int k0 = 0; k0 < D_; k0 += BK) {
        #pragma unroll
        for (int l = 0; l < 2; ++l) {           // X tile 64x32 = 512 float4
            int idx = tid + l * 256;
            int r = idx >> 3, c = (idx & 7) * 4;
            float4 v = *reinterpret_cast<const float4*>(xb + (size_t)r * D_ + k0 + c);
            *reinterpret_cast<float4*>(&Xs[r][c]) = v;
        }
        #pragma unroll
        for (int l = 0; l < 2; ++l) {           // W tile 32x64 = 512 float4
            int idx = tid + l * 256;
            int r = idx >> 4, c = (idx & 15) * 4;
            float4 v = *reinterpret_cast<const float4*>(W + (size_t)(k0 + r) * DK_ + c);
            *reinterpret_cast<float4*>(&Ws[r][c]) = v;
        }
        __syncthreads();
        #pragma unroll 8
        for (int kk = 0; kk < BK; ++kk) {
            float a0 = Xs[ty * 4 + 0][kk];
            float a1 = Xs[ty * 4 + 1][kk];
            float a2 = Xs[ty * 4 + 2][kk];
            float a3 = Xs[ty * 4 + 3][kk];
            float4 bv = *reinterpret_cast<const float4*>(&Ws[kk][tx * 4]);
            acc[0][0] += a0 * bv.x; acc[0][1] += a0 * bv.y; acc[0][2] += a0 * bv.z; acc[0][3] += a0 * bv.w;
            acc[1][0] += a1 * bv.x; acc[1][1] += a1 * bv.y; acc[1][2] += a1 * bv.z; acc[1][3] += a1 * bv.w;
            acc[2][0] += a2 * bv.x; acc[2][1] += a2 * bv.y; acc[2][2] += a2 * bv.z; acc[2][3] += a2 * bv.w;
            acc[3][0] += a3 * bv.x; acc[3][1] += a3 * bv.y; acc[3][2] += a3 * bv.z; acc[3][3] += a3 * bv.w;
        }
        __syncthreads();
    }

    // RoPE on q,k only. Thread owns cols tx*4..tx*4+3 -> two aligned even/odd pairs.
    if (sel < 2) {
        #pragma unroll
        for (int i = 0; i < 4; ++i) {
            float sf = (float)(s0 + ty * 4 + i);
            #pragma unroll
            for (int p = 0; p < 2; ++p) {
                float pairIdx = (float)(tx * 2 + p);             // 0..31
                float inv = powf(10000.0f, -pairIdx * (1.0f / 32.0f));
                float ang = sf * inv;
                float sn, cs;
                sincosf(ang, &sn, &cs);
                float e = acc[i][2 * p];
                float o = acc[i][2 * p + 1];
                acc[i][2 * p]     = e * cs - o * sn;
                acc[i][2 * p + 1] = o * cs + e * sn;
            }
        }
    }

    #pragma unroll
    for (int i = 0; i < 4; ++i) {
        int s = s0 + ty * 4 + i;
        float4 v = make_float4(acc[i][0], acc[i][1], acc[i][2], acc[i][3]);
        *reinterpret_cast<float4*>(&dst[(((size_t)b * H_ + h) * S_ + s) * DK_ + tx * 4]) = v;
    }
}

// ---------------------------------------------------------------------------
// K2: causal flash attention, fp32.
// grid = (S/64, B*H), block = 256. Each block: 64 query rows of one (b,h).
// Online softmax; P tile reuses K's LDS buffer. O written in [B,S,H*DK] layout.
// ---------------------------------------------------------------------------
__global__ __launch_bounds__(256)
void attn_kernel(const float* __restrict__ Q,
                 const float* __restrict__ K,
                 const float* __restrict__ V,
                 float* __restrict__ O)
{
    constexpr int T = 64;
    const int qt = blockIdx.x;
    const int bh = blockIdx.y;
    const int b  = bh >> 4;
    const int h  = bh & 15;
    const int q0 = qt * T;

    const float* Qb = Q + (size_t)bh * S_ * DK_;
    const float* Kb = K + (size_t)bh * S_ * DK_;
    const float* Vb = V + (size_t)bh * S_ * DK_;

    __shared__ float Qs[T][65];     // pad 65: column reads across rows conflict-free
    __shared__ float KPs[T][65];    // holds K tile, then reused for P tile
    __shared__ float Vs[T][64];     // row reads -> no pad needed

    const int tid = threadIdx.x;
    const int ty  = tid >> 4;
    const int tx  = tid & 15;

    #pragma unroll
    for (int l = 0; l < 4; ++l) {   // Q tile 64x64 = 1024 float4
        int idx = tid + l * 256;
        int r = idx >> 4, c = (idx & 15) * 4;
        float4 v = *reinterpret_cast<const float4*>(Qb + (size_t)(q0 + r) * DK_ + c);
        Qs[r][c] = v.x; Qs[r][c + 1] = v.y; Qs[r][c + 2] = v.z; Qs[r][c + 3] = v.w;
    }

    float m[4], l[4], o[4][4];
    #pragma unroll
    for (int i = 0; i < 4; ++i) {
        m[i] = -1e30f; l[i] = 0.0f;
        #pragma unroll
        for (int j = 0; j < 4; ++j) o[i][j] = 0.0f;
    }

    for (int t = 0; t <= qt; ++t) {
        __syncthreads();            // prior iteration's KPs/Vs reads complete
        #pragma unroll
        for (int l2 = 0; l2 < 4; ++l2) {
            int idx = tid + l2 * 256;
            int r = idx >> 4, c = (idx & 15) * 4;
            float4 kv = *reinterpret_cast<const float4*>(Kb + (size_t)(t * T + r) * DK_ + c);
            KPs[r][c] = kv.x; KPs[r][c + 1] = kv.y; KPs[r][c + 2] = kv.z; KPs[r][c + 3] = kv.w;
            float4 vv = *reinterpret_cast<const float4*>(Vb + (size_t)(t * T + r) * DK_ + c);
            Vs[r][c] = vv.x; Vs[r][c + 1] = vv.y; Vs[r][c + 2] = vv.z; Vs[r][c + 3] = vv.w;
        }
        __syncthreads();

        // S = Q @ K^T (inner dim 64)
        float sc[4][4] = {};
        #pragma unroll 4
        for (int kk = 0; kk < DK_; ++kk) {
            float a[4], bb[4];
            #pragma unroll
            for (int i = 0; i < 4; ++i) a[i]  = Qs[ty * 4 + i][kk];
            #pragma unroll
            for (int j = 0; j < 4; ++j) bb[j] = KPs[tx * 4 + j][kk];
            #pragma unroll
            for (int i = 0; i < 4; ++i)
                #pragma unroll
                for (int j = 0; j < 4; ++j)
                    sc[i][j] += a[i] * bb[j];
        }

        const bool diag = (t == qt);
        #pragma unroll
        for (int i = 0; i < 4; ++i) {
            #pragma unroll
            for (int j = 0; j < 4; ++j) {
                float s = sc[i][j] * 0.125f;                    // 1/sqrt(64)
                if (diag && (tx * 4 + j) > (ty * 4 + i)) s = -1e30f;
                sc[i][j] = s;
            }
        }

        // online softmax: row stats across the 16 tx lanes (contiguous in wave)
        #pragma unroll
        for (int i = 0; i < 4; ++i) {
            float pm = fmaxf(fmaxf(sc[i][0], sc[i][1]), fmaxf(sc[i][2], sc[i][3]));
            pm = fmaxf(pm, __shfl_xor(pm, 1));
            pm = fmaxf(pm, __shfl_xor(pm, 2));
            pm = fmaxf(pm, __shfl_xor(pm, 4));
            pm = fmaxf(pm, __shfl_xor(pm, 8));
            float mn = fmaxf(m[i], pm);
            float alpha = __expf(m[i] - mn);
            float rs = 0.0f;
            #pragma unroll
            for (int j = 0; j < 4; ++j) {
                sc[i][j] = __expf(sc[i][j] - mn);
                rs += sc[i][j];
            }
            rs += __shfl_xor(rs, 1);
            rs += __shfl_xor(rs, 2);
            rs += __shfl_xor(rs, 4);
            rs += __shfl_xor(rs, 8);
            l[i] = l[i] * alpha + rs;
            m[i] = mn;
            #pragma unroll
            for (int j = 0; j < 4; ++j) o[i][j] *= alpha;
        }

        __syncthreads();            // everyone done reading K before P overwrites it
        #pragma unroll
        for (int i = 0; i < 4; ++i)
            #pragma unroll
            for (int j = 0; j < 4; ++j)
                KPs[ty * 4 + i][tx * 4 + j] = sc[i][j];
        __syncthreads();

        // O += P @ V (inner dim 64)
        #pragma unroll 4
        for (int kr = 0; kr < T; ++kr) {
            float a[4], vv[4];
            #pragma unroll
            for (int i = 0; i < 4; ++i) a[i]  = KPs[ty * 4 + i][kr];
            #pragma unroll
            for (int j = 0; j < 4; ++j) vv[j] = Vs[kr][tx * 4 + j];
            #pragma unroll
            for (int i = 0; i < 4; ++i)
                #pragma unroll
                for (int j = 0; j < 4; ++j)
                    o[i][j] += a[i] * vv[j];
        }
    }

    #pragma unroll
    for (int i = 0; i < 4; ++i) {
        float invl = 1.0f / l[i];
        int s = q0 + ty * 4 + i;
        float4 v = make_float4(o[i][0] * invl, o[i][1] * invl,
                               o[i][2] * invl, o[i][3] * invl);
        *reinterpret_cast<float4*>(&O[((size_t)b * S_ + s) * D_ + h * DK_ + tx * 4]) = v;
    }
}

// ---------------------------------------------------------------------------
// K3: output projection C[B*S, D] = A[B*S, D] @ Wo[D, D]
// grid = (B*S/64, D/64), block = 256. Same structure as K1, no RoPE.
// ---------------------------------------------------------------------------
__global__ __launch_bounds__(256)
void out_proj_kernel(const float* __restrict__ A,
                     const float* __restrict__ Wo,
                     float* __restrict__ C)
{
    constexpr int TS = 64, BK = 32;
    const int m0 = blockIdx.x * TS;
    const int n0 = blockIdx.y * TS;

    __shared__ float As[TS][36];
    __shared__ float Bs[BK][TS];

    const int tid = threadIdx.x;
    const int ty  = tid >> 4;
    const int tx  = tid & 15;

    float acc[4][4] = {};

    for (int k0 = 0; k0 < D_; k0 += BK) {
        #pragma unroll
        for (int l = 0; l < 2; ++l) {
            int idx = tid + l * 256;
            int r = idx >> 3, c = (idx & 7) * 4;
            float4 v = *reinterpret_cast<const float4*>(A + (size_t)(m0 + r) * D_ + k0 + c);
            *reinterpret_cast<float4*>(&As[r][c]) = v;
        }
        #pragma unroll
        for (int l = 0; l < 2; ++l) {
            int idx = tid + l * 256;
            int r = idx >> 4, c = (idx & 15) * 4;
            float4 v = *reinterpret_cast<const float4*>(Wo + (size_t)(k0 + r) * D_ + n0 + c);
            *reinterpret_cast<float4*>(&Bs[r][c]) = v;
        }
        __syncthreads();
        #pragma unroll 8
        for (int kk = 0; kk < BK; ++kk) {
            float a0 = As[ty * 4 + 0][kk];
            float a1 = As[ty * 4 + 1][kk];
            float a2 = As[ty * 4 + 2][kk];
            float a3 = As[ty * 4 + 3][kk];
            float4 bv = *reinterpret_cast<const float4*>(&Bs[kk][tx * 4]);
            acc[0][0] += a0 * bv.x; acc[0][1] += a0 * bv.y; acc[0][2] += a0 * bv.z; acc[0][3] += a0 * bv.w;
            acc[1][0] += a1 * bv.x; acc[1][1] += a1 * bv.y; acc[1][2] += a1 * bv.z; acc[1][3] += a1 * bv.w;
            acc[2][0] += a2 * bv.x; acc[2][1] += a2 * bv.y; acc[2][2] += a2 * bv.z; acc[2][3] += a2 * bv.w;
            acc[3][0] += a3 * bv.x; acc[3][1] += a3 * bv.y; acc[3][2] += a3 * bv.z; acc[3][3] += a3 * bv.w;
        }
        __syncthreads();
    }

    #pragma unroll
    for (int i = 0; i < 4; ++i) {
        float4 v = make_float4(acc[i][0], acc[i][1], acc[i][2], acc[i][3]);
        *reinterpret_cast<float4*>(&C[(size_t)(m0 + ty * 4 + i) * D_ + n0 + tx * 4]) = v;
    }
}

} // anonymous namespace

extern "C" void kernel_launch(void* const* d_in, const int* in_sizes, int n_in,
                              void* d_out, int out_size, void* d_ws, size_t ws_size,
                              hipStream_t stream)
{
    const float* x  = (const float*)d_in[0];
    const float* Wq = (const float*)d_in[1];
    const float* Wk = (const float*)d_in[2];
    const float* Wv = (const float*)d_in[3];
    const float* Wo = (const float*)d_in[4];
    float* out = (float*)d_out;

    const size_t qkvElems = (size_t)B_ * H_ * S_ * DK_;   // 4,194,304 floats (16 MB)
    float* Q = (float*)d_ws;
    float* K = Q + qkvElems;
    float* V = K + qkvElems;
    float* O = V + qkvElems;                              // [B, S, H*DK] attn output

    qkv_rope_kernel<<<dim3(B_ * S_ / 64, H_, 3), 256, 0, stream>>>(x, Wq, Wk, Wv, Q, K, V);
    attn_kernel<<<dim3(S_ / 64, B_ * H_), 256, 0, stream>>>(Q, K, V, O);
    out_proj_kernel<<<dim3(B_ * S_ / 64, D_ / 64), 256, 0, stream>>>(O, Wo, out);
}

// Round 2
// 230.881 us; speedup vs baseline: 4.6338x; 4.6338x over previous
//
#include <hip/hip_runtime.h>
#include <math.h>

typedef __attribute__((ext_vector_type(8))) short bf16x8;
typedef __attribute__((ext_vector_type(4))) float f32x4;
typedef unsigned short ushort_t;
typedef unsigned int uint_t;

typedef const void __attribute__((address_space(1)))* gas_ptr;
typedef void __attribute__((address_space(3)))* las_ptr;

namespace {

constexpr int S_  = 2048;
constexpr int D_  = 1024;

__device__ inline ushort_t f2bf(float f) {
    uint_t u = __builtin_bit_cast(uint_t, f);
    u += 0x7FFFu + ((u >> 16) & 1u);
    return (ushort_t)(u >> 16);
}
__device__ inline float bf2f(ushort_t b) {
    uint_t u = ((uint_t)b) << 16;
    return __builtin_bit_cast(float, u);
}

// ---------------------------------------------------------------------------
// convert fp32 -> bf16, 8 elems/thread
// ---------------------------------------------------------------------------
__global__ __launch_bounds__(256)
void conv_kernel(const float* __restrict__ src, ushort_t* __restrict__ dst)
{
    int i = blockIdx.x * 256 + threadIdx.x;
    float4 a = ((const float4*)src)[i * 2];
    float4 b = ((const float4*)src)[i * 2 + 1];
    uint_t u0 = (uint_t)f2bf(a.x) | ((uint_t)f2bf(a.y) << 16);
    uint_t u1 = (uint_t)f2bf(a.z) | ((uint_t)f2bf(a.w) << 16);
    uint_t u2 = (uint_t)f2bf(b.x) | ((uint_t)f2bf(b.y) << 16);
    uint_t u3 = (uint_t)f2bf(b.z) | ((uint_t)f2bf(b.w) << 16);
    uint4 st = make_uint4(u0, u1, u2, u3);
    ((uint4*)dst)[i] = st;
}

// ---------------------------------------------------------------------------
// transpose + convert: src fp32 [R][C] -> dst bf16 [C][R], 64x64 tiles.
// grid (R/64, C/64, Z); per-z strides for per-head weight transposes.
// ---------------------------------------------------------------------------
__global__ __launch_bounds__(256)
void tconv_kernel(const float* __restrict__ src, ushort_t* __restrict__ dst,
                  int R, int C, long zss, long zds)
{
    __shared__ float Tl[64][65];
    src += (size_t)blockIdx.z * zss;
    dst += (size_t)blockIdx.z * zds;
    const int r0 = blockIdx.x * 64, c0 = blockIdx.y * 64;
    const int tid = threadIdx.x;
    #pragma unroll
    for (int l = 0; l < 4; ++l) {
        int i = tid + l * 256;
        int row = i >> 4, col = (i & 15) * 4;
        float4 v = *(const float4*)(src + (size_t)(r0 + row) * C + c0 + col);
        Tl[row][col] = v.x; Tl[row][col + 1] = v.y;
        Tl[row][col + 2] = v.z; Tl[row][col + 3] = v.w;
    }
    __syncthreads();
    #pragma unroll
    for (int l = 0; l < 4; ++l) {
        int i = tid + l * 256;
        int cc = i >> 4, rr = (i & 15) * 4;
        uint_t lo = (uint_t)f2bf(Tl[rr][cc])     | ((uint_t)f2bf(Tl[rr + 1][cc]) << 16);
        uint_t hi = (uint_t)f2bf(Tl[rr + 2][cc]) | ((uint_t)f2bf(Tl[rr + 3][cc]) << 16);
        *(uint2*)(dst + (size_t)(c0 + cc) * R + r0 + rr) = make_uint2(lo, hi);
    }
}

// ---------------------------------------------------------------------------
// RoPE in-place on bf16 [BH][S][DK=64]; 4 elems (2 pairs) per thread.
// ---------------------------------------------------------------------------
__global__ __launch_bounds__(256)
void rope_kernel(ushort_t* __restrict__ T)
{
    int i = blockIdx.x * 256 + threadIdx.x;
    int flat = i * 4;
    int dk = flat & 63;
    int s  = (flat >> 6) & 2047;
    uint2 lv = *(uint2*)(T + flat);
    float e0 = bf2f((ushort_t)(lv.x & 0xffff));
    float o0 = bf2f((ushort_t)(lv.x >> 16));
    float e1 = bf2f((ushort_t)(lv.y & 0xffff));
    float o1 = bf2f((ushort_t)(lv.y >> 16));
    int p0 = dk >> 1;
    float inv0 = powf(10000.0f, -(float)p0 * (1.0f / 32.0f));
    float inv1 = powf(10000.0f, -(float)(p0 + 1) * (1.0f / 32.0f));
    float sf = (float)s;
    float sn0, cs0, sn1, cs1;
    sincosf(sf * inv0, &sn0, &cs0);
    sincosf(sf * inv1, &sn1, &cs1);
    float r0 = e0 * cs0 - o0 * sn0;
    float r1 = o0 * cs0 + e0 * sn0;
    float r2 = e1 * cs1 - o1 * sn1;
    float r3 = o1 * cs1 + e1 * sn1;
    uint_t w0 = (uint_t)f2bf(r0) | ((uint_t)f2bf(r1) << 16);
    uint_t w1 = (uint_t)f2bf(r2) | ((uint_t)f2bf(r3) << 16);
    *(uint2*)(T + flat) = make_uint2(w0, w1);
}

// ---------------------------------------------------------------------------
// m97-style bf16 MFMA GEMM: C[M][N] = A[M][K] * Bt[N][K]^T
// 128x128 tile, BK=32, 4 waves (2x2), global_load_lds width 16.
// MODE 0: QKV epilogue -> Q,K as [bh][s][64] bf16, V as [bh][64][s] bf16 (transposed)
// MODE 1: fp32 epilogue -> Co[M][N]
// ---------------------------------------------------------------------------
template<int MODE>
__global__ __launch_bounds__(256)
void gemm_kernel(const ushort_t* __restrict__ A, const ushort_t* __restrict__ Bt,
                 ushort_t* __restrict__ Qo, ushort_t* __restrict__ Ko,
                 ushort_t* __restrict__ Vto, float* __restrict__ Co, int K)
{
    __shared__ ushort_t As[128 * 32];
    __shared__ ushort_t Bs[128 * 32];

    const int tid  = threadIdx.x;
    const int w    = tid >> 6, lane = tid & 63;
    const int lq   = lane & 15, lk = lane >> 4;
    const int wr   = w >> 1, wc = w & 1;
    const int m0   = blockIdx.x * 128;
    const int n0   = blockIdx.y * 128;

    f32x4 acc[4][4] = {};

    for (int k0 = 0; k0 < K; k0 += 32) {
        #pragma unroll
        for (int i = 0; i < 2; ++i) {
            int c   = i * 256 + tid;
            int row = c >> 2, c4 = c & 3;
            const ushort_t* ga = A  + (size_t)(m0 + row) * K + k0 + c4 * 8;
            const ushort_t* gb = Bt + (size_t)(n0 + row) * K + k0 + c4 * 8;
            int base = (i * 256 + w * 64) * 16;
            __builtin_amdgcn_global_load_lds((gas_ptr)ga, (las_ptr)((char*)As + base), 16, 0, 0);
            __builtin_amdgcn_global_load_lds((gas_ptr)gb, (las_ptr)((char*)Bs + base), 16, 0, 0);
        }
        __syncthreads();

        bf16x8 a[4], b[4];
        #pragma unroll
        for (int m = 0; m < 4; ++m)
            a[m] = *(const bf16x8*)((const char*)As + (wr * 64 + m * 16 + lq) * 64 + lk * 16);
        #pragma unroll
        for (int n = 0; n < 4; ++n)
            b[n] = *(const bf16x8*)((const char*)Bs + (wc * 64 + n * 16 + lq) * 64 + lk * 16);
        #pragma unroll
        for (int m = 0; m < 4; ++m)
            #pragma unroll
            for (int n = 0; n < 4; ++n)
                acc[m][n] = __builtin_amdgcn_mfma_f32_16x16x32_bf16(a[m], b[n], acc[m][n], 0, 0, 0);
        __syncthreads();
    }

    if (MODE == 0) {
        const int sel = n0 >> 10;
        ushort_t* dst = (sel == 0) ? Qo : (sel == 1) ? Ko : Vto;
        #pragma unroll
        for (int m = 0; m < 4; ++m) {
            #pragma unroll
            for (int r = 0; r < 4; ++r) {
                int mg = m0 + wr * 64 + m * 16 + lk * 4 + r;
                int b_ = mg >> 11, s = mg & 2047;
                #pragma unroll
                for (int n = 0; n < 4; ++n) {
                    int ng = n0 + wc * 64 + n * 16 + lq;
                    int h = (ng >> 6) & 15, dk = ng & 63;
                    ushort_t v = f2bf(acc[m][n][r]);
                    if (sel < 2)
                        dst[(((size_t)b_ * 16 + h) * 2048 + s) * 64 + dk] = v;
                    else
                        dst[(((size_t)b_ * 16 + h) * 64 + dk) * 2048 + s] = v;
                }
            }
        }
    } else {
        #pragma unroll
        for (int m = 0; m < 4; ++m) {
            #pragma unroll
            for (int r = 0; r < 4; ++r) {
                int mg = m0 + wr * 64 + m * 16 + lk * 4 + r;
                #pragma unroll
                for (int n = 0; n < 4; ++n) {
                    int ng = n0 + wc * 64 + n * 16 + lq;
                    Co[(size_t)mg * D_ + ng] = acc[m][n][r];
                }
            }
        }
    }
}

// ---------------------------------------------------------------------------
// MFMA causal flash attention.
// grid (S/64, B*H), 256 threads = 4 waves; wave w owns q-rows [w*16, w*16+16).
// K tile [64 kv][64 dk] and V^T tile [64 dk][64 kv] in XOR-swizzled LDS.
// Online softmax in registers; P transposed through per-wave LDS buffer.
// ---------------------------------------------------------------------------
__global__ __launch_bounds__(256)
void attn_kernel(const ushort_t* __restrict__ Q, const ushort_t* __restrict__ Kg,
                 const ushort_t* __restrict__ Vt, ushort_t* __restrict__ O)
{
    __shared__ ushort_t Ks[64 * 64];
    __shared__ ushort_t Vs[64 * 64];
    __shared__ ushort_t Ps[4][16 * 64];

    const int qt = blockIdx.x, bh = blockIdx.y;
    const int tid = threadIdx.x;
    const int w = tid >> 6, lane = tid & 63;
    const int lq = lane & 15, lk = lane >> 4;
    const int q0 = qt * 64;
    const size_t bhBase = (size_t)bh * S_ * 64;

    bf16x8 qa[2];
    {
        const ushort_t* qp = Q + bhBase + (size_t)(q0 + w * 16 + lq) * 64 + lk * 8;
        qa[0] = *(const bf16x8*)(qp);
        qa[1] = *(const bf16x8*)(qp + 32);
    }

    float mrow[4], lrow[4];
    f32x4 accO[4] = {};
    #pragma unroll
    for (int r = 0; r < 4; ++r) { mrow[r] = -1e30f; lrow[r] = 0.0f; }

    for (int t = 0; t <= qt; ++t) {
        #pragma unroll
        for (int i = 0; i < 2; ++i) {
            int c = i * 256 + tid;
            int rr = c >> 3, c8 = c & 7;
            bf16x8 kvv = *(const bf16x8*)(Kg + bhBase + (size_t)(t * 64 + rr) * 64 + c8 * 8);
            int koff = rr * 128 + ((c8 * 16) ^ ((rr & 7) << 4));
            *(bf16x8*)((char*)Ks + koff) = kvv;
            bf16x8 vvv = *(const bf16x8*)(Vt + bhBase + (size_t)rr * 2048 + t * 64 + c8 * 8);
            *(bf16x8*)((char*)Vs + koff) = vvv;
        }
        __syncthreads();

        // S = Q K^T
        f32x4 sf[4];
        #pragma unroll
        for (int n = 0; n < 4; ++n) {
            int row = n * 16 + lq;           // kv index
            f32x4 acc = {};
            #pragma unroll
            for (int ks = 0; ks < 2; ++ks) {
                int off = row * 128 + (((ks * 64) + lk * 16) ^ ((row & 7) << 4));
                bf16x8 kb = *(const bf16x8*)((const char*)Ks + off);
                acc = __builtin_amdgcn_mfma_f32_16x16x32_bf16(qa[ks], kb, acc, 0, 0, 0);
            }
            sf[n] = acc;
        }

        if (t == qt) {
            #pragma unroll
            for (int n = 0; n < 4; ++n)
                #pragma unroll
                for (int r = 0; r < 4; ++r) {
                    int kv = t * 64 + n * 16 + lq;
                    int qr = q0 + w * 16 + lk * 4 + r;
                    float s = sf[n][r] * 0.125f;
                    sf[n][r] = (kv > qr) ? -1e30f : s;
                }
        } else {
            #pragma unroll
            for (int n = 0; n < 4; ++n)
                #pragma unroll
                for (int r = 0; r < 4; ++r) sf[n][r] *= 0.125f;
        }

        #pragma unroll
        for (int r = 0; r < 4; ++r) {
            float pm = fmaxf(fmaxf(sf[0][r], sf[1][r]), fmaxf(sf[2][r], sf[3][r]));
            pm = fmaxf(pm, __shfl_xor(pm, 1));
            pm = fmaxf(pm, __shfl_xor(pm, 2));
            pm = fmaxf(pm, __shfl_xor(pm, 4));
            pm = fmaxf(pm, __shfl_xor(pm, 8));
            float mn = fmaxf(mrow[r], pm);
            float alpha = __expf(mrow[r] - mn);
            mrow[r] = mn;
            float rs = 0.0f;
            #pragma unroll
            for (int n = 0; n < 4; ++n) {
                float p = __expf(sf[n][r] - mn);
                sf[n][r] = p;
                rs += p;
            }
            rs += __shfl_xor(rs, 1);
            rs += __shfl_xor(rs, 2);
            rs += __shfl_xor(rs, 4);
            rs += __shfl_xor(rs, 8);
            lrow[r] = lrow[r] * alpha + rs;
            #pragma unroll
            for (int n = 0; n < 4; ++n) accO[n][r] *= alpha;
        }

        // write P (bf16) to per-wave swizzled LDS buffer
        #pragma unroll
        for (int r = 0; r < 4; ++r) {
            int prow = lk * 4 + r;
            #pragma unroll
            for (int n = 0; n < 4; ++n) {
                int off = prow * 128 + (((n * 16 + lq) * 2) ^ ((prow & 7) << 4));
                *(ushort_t*)((char*)Ps[w] + off) = f2bf(sf[n][r]);
            }
        }
        asm volatile("s_waitcnt lgkmcnt(0)" ::: "memory");

        // O += P V
        #pragma unroll
        for (int ks = 0; ks < 2; ++ks) {
            int poff = lq * 128 + (((ks * 64) + lk * 16) ^ ((lq & 7) << 4));
            bf16x8 pa = *(const bf16x8*)((const char*)Ps[w] + poff);
            #pragma unroll
            for (int n = 0; n < 4; ++n) {
                int row = n * 16 + lq;       // dk index
                int voff = row * 128 + (((ks * 64) + lk * 16) ^ ((row & 7) << 4));
                bf16x8 vb = *(const bf16x8*)((const char*)Vs + voff);
                accO[n] = __builtin_amdgcn_mfma_f32_16x16x32_bf16(pa, vb, accO[n], 0, 0, 0);
            }
        }
        __syncthreads();
    }

    const int b_ = bh >> 4, h = bh & 15;
    #pragma unroll
    for (int r = 0; r < 4; ++r) {
        float inv = 1.0f / lrow[r];
        int s = q0 + w * 16 + lk * 4 + r;
        size_t base = ((size_t)b_ * 2048 + s) * 1024 + h * 64;
        #pragma unroll
        for (int n = 0; n < 4; ++n)
            O[base + n * 16 + lq] = f2bf(accO[n][r] * inv);
    }
}

} // anonymous namespace

extern "C" void kernel_launch(void* const* d_in, const int* in_sizes, int n_in,
                              void* d_out, int out_size, void* d_ws, size_t ws_size,
                              hipStream_t stream)
{
    const float* x  = (const float*)d_in[0];
    const float* Wq = (const float*)d_in[1];
    const float* Wk = (const float*)d_in[2];
    const float* Wv = (const float*)d_in[3];
    const float* Wo = (const float*)d_in[4];

    ushort_t* xb  = (ushort_t*)d_ws;              // [4096][1024]        4M elems
    ushort_t* Wt  = xb  + 4194304;                // [3072][1024] (B^T)  3M elems
    ushort_t* Wot = Wt  + 3145728;                // [1024][1024] (B^T)  1M elems
    ushort_t* Qb  = Wot + 1048576;                // [32][2048][64]      4M elems
    ushort_t* Kb  = Qb  + 4194304;                // [32][2048][64]      4M elems
    ushort_t* Vtb = Kb  + 4194304;                // [32][64][2048]      4M elems
    ushort_t* Ob  = Vtb + 4194304;                // [4096][1024]        4M elems

    conv_kernel<<<2048, 256, 0, stream>>>(x, xb);
    tconv_kernel<<<dim3(16, 1, 16), 256, 0, stream>>>(Wq, Wt,           1024, 64, 65536, 65536);
    tconv_kernel<<<dim3(16, 1, 16), 256, 0, stream>>>(Wk, Wt + 1048576, 1024, 64, 65536, 65536);
    tconv_kernel<<<dim3(16, 1, 16), 256, 0, stream>>>(Wv, Wt + 2097152, 1024, 64, 65536, 65536);
    tconv_kernel<<<dim3(16, 16, 1), 256, 0, stream>>>(Wo, Wot,          1024, 1024, 0, 0);

    gemm_kernel<0><<<dim3(32, 24), 256, 0, stream>>>(xb, Wt, Qb, Kb, Vtb, nullptr, 1024);

    rope_kernel<<<4096, 256, 0, stream>>>(Qb);
    rope_kernel<<<4096, 256, 0, stream>>>(Kb);

    attn_kernel<<<dim3(32, 32), 256, 0, stream>>>(Qb, Kb, Vtb, Ob);

    gemm_kernel<1><<<dim3(32, 8), 256, 0, stream>>>(Ob, Wot, nullptr, nullptr, nullptr,
                                                    (float*)d_out, 1024);
}

// Round 3
// 187.615 us; speedup vs baseline: 5.7024x; 1.2306x over previous
//
#include <hip/hip_runtime.h>
#include <math.h>

typedef __attribute__((ext_vector_type(8))) short bf16x8;
typedef __attribute__((ext_vector_type(4))) float f32x4;
typedef unsigned short ushort_t;
typedef unsigned int uint_t;

typedef const void __attribute__((address_space(1)))* gas_ptr;
typedef void __attribute__((address_space(3)))* las_ptr;

namespace {

constexpr int S_  = 2048;
constexpr int D_  = 1024;

__device__ inline ushort_t f2bf(float f) {
    uint_t u = __builtin_bit_cast(uint_t, f);
    u += 0x7FFFu + ((u >> 16) & 1u);
    return (ushort_t)(u >> 16);
}
__device__ inline float bf2f(ushort_t b) {
    uint_t u = ((uint_t)b) << 16;
    return __builtin_bit_cast(float, u);
}

// ---------------------------------------------------------------------------
// convert fp32 -> bf16, 8 elems/thread
// ---------------------------------------------------------------------------
__global__ __launch_bounds__(256)
void conv_kernel(const float* __restrict__ src, ushort_t* __restrict__ dst)
{
    int i = blockIdx.x * 256 + threadIdx.x;
    float4 a = ((const float4*)src)[i * 2];
    float4 b = ((const float4*)src)[i * 2 + 1];
    uint_t u0 = (uint_t)f2bf(a.x) | ((uint_t)f2bf(a.y) << 16);
    uint_t u1 = (uint_t)f2bf(a.z) | ((uint_t)f2bf(a.w) << 16);
    uint_t u2 = (uint_t)f2bf(b.x) | ((uint_t)f2bf(b.y) << 16);
    uint_t u3 = (uint_t)f2bf(b.z) | ((uint_t)f2bf(b.w) << 16);
    ((uint4*)dst)[i] = make_uint4(u0, u1, u2, u3);
}

// ---------------------------------------------------------------------------
// transpose + convert: src fp32 [R][C] -> dst bf16 [C][R], 64x64 tiles.
// ---------------------------------------------------------------------------
__global__ __launch_bounds__(256)
void tconv_kernel(const float* __restrict__ src, ushort_t* __restrict__ dst,
                  int R, int C, long zss, long zds)
{
    __shared__ float Tl[64][65];
    src += (size_t)blockIdx.z * zss;
    dst += (size_t)blockIdx.z * zds;
    const int r0 = blockIdx.x * 64, c0 = blockIdx.y * 64;
    const int tid = threadIdx.x;
    #pragma unroll
    for (int l = 0; l < 4; ++l) {
        int i = tid + l * 256;
        int row = i >> 4, col = (i & 15) * 4;
        float4 v = *(const float4*)(src + (size_t)(r0 + row) * C + c0 + col);
        Tl[row][col] = v.x; Tl[row][col + 1] = v.y;
        Tl[row][col + 2] = v.z; Tl[row][col + 3] = v.w;
    }
    __syncthreads();
    #pragma unroll
    for (int l = 0; l < 4; ++l) {
        int i = tid + l * 256;
        int cc = i >> 4, rr = (i & 15) * 4;
        uint_t lo = (uint_t)f2bf(Tl[rr][cc])     | ((uint_t)f2bf(Tl[rr + 1][cc]) << 16);
        uint_t hi = (uint_t)f2bf(Tl[rr + 2][cc]) | ((uint_t)f2bf(Tl[rr + 3][cc]) << 16);
        *(uint2*)(dst + (size_t)(c0 + cc) * R + r0 + rr) = make_uint2(lo, hi);
    }
}

// ---------------------------------------------------------------------------
// RoPE cos/sin table: tbl[s][p] = (cos, sin) of s * theta^(-p/32), 2048 x 32
// ---------------------------------------------------------------------------
__global__ __launch_bounds__(256)
void rope_table_kernel(float* __restrict__ tbl)
{
    int i = blockIdx.x * 256 + threadIdx.x;     // 65536 entries
    int s = i >> 5, p = i & 31;
    float inv = powf(10000.0f, -(float)p * (1.0f / 32.0f));
    float sn, cs;
    sincosf((float)s * inv, &sn, &cs);
    ((float2*)tbl)[i] = make_float2(cs, sn);
}

// ---------------------------------------------------------------------------
// RoPE in-place on bf16 [BH][S][DK=64]; 4 elems (2 pairs) / thread, table-read.
// ---------------------------------------------------------------------------
__global__ __launch_bounds__(256)
void rope_kernel(ushort_t* __restrict__ T, const float* __restrict__ tbl)
{
    int i = blockIdx.x * 256 + threadIdx.x;
    int flat = i * 4;
    int dk = flat & 63;
    int s  = (flat >> 6) & 2047;
    int p0 = dk >> 1;                            // even
    float4 cssn = *(const float4*)(tbl + ((size_t)s * 32 + p0) * 2);
    uint2 lv = *(uint2*)(T + flat);
    float e0 = bf2f((ushort_t)(lv.x & 0xffff));
    float o0 = bf2f((ushort_t)(lv.x >> 16));
    float e1 = bf2f((ushort_t)(lv.y & 0xffff));
    float o1 = bf2f((ushort_t)(lv.y >> 16));
    float r0 = e0 * cssn.x - o0 * cssn.y;
    float r1 = o0 * cssn.x + e0 * cssn.y;
    float r2 = e1 * cssn.z - o1 * cssn.w;
    float r3 = o1 * cssn.z + e1 * cssn.w;
    uint_t w0 = (uint_t)f2bf(r0) | ((uint_t)f2bf(r1) << 16);
    uint_t w1 = (uint_t)f2bf(r2) | ((uint_t)f2bf(r3) << 16);
    *(uint2*)(T + flat) = make_uint2(w0, w1);
}

// ---------------------------------------------------------------------------
// m97-style bf16 MFMA GEMM: C[M][N] = A[M][K] * Bt[N][K]^T
// 128x128 tile, BK=32, 4 waves (2x2), global_load_lds width 16.
// MODE 0: QKV epilogue -> Q,K as [bh][s][64] bf16, V as [bh][64][s] bf16
// MODE 1: fp32 epilogue -> Co[M][N]
// ---------------------------------------------------------------------------
template<int MODE>
__global__ __launch_bounds__(256)
void gemm_kernel(const ushort_t* __restrict__ A, const ushort_t* __restrict__ Bt,
                 ushort_t* __restrict__ Qo, ushort_t* __restrict__ Ko,
                 ushort_t* __restrict__ Vto, float* __restrict__ Co, int K)
{
    __shared__ ushort_t As[128 * 32];
    __shared__ ushort_t Bs[128 * 32];

    const int tid  = threadIdx.x;
    const int w    = tid >> 6, lane = tid & 63;
    const int lq   = lane & 15, lk = lane >> 4;
    const int wr   = w >> 1, wc = w & 1;
    const int m0   = blockIdx.x * 128;
    const int n0   = blockIdx.y * 128;

    f32x4 acc[4][4] = {};

    for (int k0 = 0; k0 < K; k0 += 32) {
        #pragma unroll
        for (int i = 0; i < 2; ++i) {
            int c   = i * 256 + tid;
            int row = c >> 2, c4 = c & 3;
            const ushort_t* ga = A  + (size_t)(m0 + row) * K + k0 + c4 * 8;
            const ushort_t* gb = Bt + (size_t)(n0 + row) * K + k0 + c4 * 8;
            int base = (i * 256 + w * 64) * 16;
            __builtin_amdgcn_global_load_lds((gas_ptr)ga, (las_ptr)((char*)As + base), 16, 0, 0);
            __builtin_amdgcn_global_load_lds((gas_ptr)gb, (las_ptr)((char*)Bs + base), 16, 0, 0);
        }
        __syncthreads();

        bf16x8 a[4], b[4];
        #pragma unroll
        for (int m = 0; m < 4; ++m)
            a[m] = *(const bf16x8*)((const char*)As + (wr * 64 + m * 16 + lq) * 64 + lk * 16);
        #pragma unroll
        for (int n = 0; n < 4; ++n)
            b[n] = *(const bf16x8*)((const char*)Bs + (wc * 64 + n * 16 + lq) * 64 + lk * 16);
        #pragma unroll
        for (int m = 0; m < 4; ++m)
            #pragma unroll
            for (int n = 0; n < 4; ++n)
                acc[m][n] = __builtin_amdgcn_mfma_f32_16x16x32_bf16(a[m], b[n], acc[m][n], 0, 0, 0);
        __syncthreads();
    }

    if (MODE == 0) {
        const int sel = n0 >> 10;
        ushort_t* dst = (sel == 0) ? Qo : (sel == 1) ? Ko : Vto;
        #pragma unroll
        for (int m = 0; m < 4; ++m) {
            #pragma unroll
            for (int r = 0; r < 4; ++r) {
                int mg = m0 + wr * 64 + m * 16 + lk * 4 + r;
                int b_ = mg >> 11, s = mg & 2047;
                #pragma unroll
                for (int n = 0; n < 4; ++n) {
                    int ng = n0 + wc * 64 + n * 16 + lq;
                    int h = (ng >> 6) & 15, dk = ng & 63;
                    ushort_t v = f2bf(acc[m][n][r]);
                    if (sel < 2)
                        dst[(((size_t)b_ * 16 + h) * 2048 + s) * 64 + dk] = v;
                    else
                        dst[(((size_t)b_ * 16 + h) * 64 + dk) * 2048 + s] = v;
                }
            }
        }
    } else {
        #pragma unroll
        for (int m = 0; m < 4; ++m) {
            #pragma unroll
            for (int r = 0; r < 4; ++r) {
                int mg = m0 + wr * 64 + m * 16 + lk * 4 + r;
                #pragma unroll
                for (int n = 0; n < 4; ++n) {
                    int ng = n0 + wc * 64 + n * 16 + lq;
                    Co[(size_t)mg * D_ + ng] = acc[m][n][r];
                }
            }
        }
    }
}

// ---------------------------------------------------------------------------
// MFMA causal flash attention, double-buffered, 1 barrier/iter.
// grid 1024 blocks (zigzag qt map for load balance), 256 thr = 4 waves.
// Wave w owns q-rows [w*16, w*16+16). K tile [64 kv][64 dk], V^T tile
// [64 dk][64 kv] in XOR-swizzled LDS, reg-prefetched one tile ahead.
// exp2-domain online softmax with defer-max (THR=11.5 in log2).
// ---------------------------------------------------------------------------
__global__ __launch_bounds__(256)
void attn_kernel(const ushort_t* __restrict__ Q, const ushort_t* __restrict__ Kg,
                 const ushort_t* __restrict__ Vt, ushort_t* __restrict__ O)
{
    __shared__ ushort_t Ks[2][64 * 64];
    __shared__ ushort_t Vs[2][64 * 64];
    __shared__ ushort_t Ps[4][16 * 64];

    // zigzag map: per-CU resident work ~constant, longest blocks first
    const int bid = blockIdx.x;
    const int g = bid >> 8, ii = bid & 255;
    const int r8 = ii >> 3;
    const int qt = (g & 1) ? r8 : 31 - r8;
    const int bh = (ii & 7) | (g << 3);

    const int tid = threadIdx.x;
    const int w = tid >> 6, lane = tid & 63;
    const int lq = lane & 15, lk = lane >> 4;
    const int q0 = qt * 64;
    const size_t bhBase = (size_t)bh * S_ * 64;

    // staging geometry (2 x bf16x8 per thread per tensor)
    const int rr0 = tid >> 3, c8 = tid & 7;
    const int rr1 = rr0 + 32;
    const int koff0 = rr0 * 128 + ((c8 * 16) ^ ((rr0 & 7) << 4));
    const int koff1 = rr1 * 128 + ((c8 * 16) ^ ((rr1 & 7) << 4));

    bf16x8 qa[2];
    {
        const ushort_t* qp = Q + bhBase + (size_t)(q0 + w * 16 + lq) * 64 + lk * 8;
        qa[0] = *(const bf16x8*)(qp);
        qa[1] = *(const bf16x8*)(qp + 32);
    }

    // prologue: tile 0 -> regs -> LDS buf 0
    bf16x8 kr0 = *(const bf16x8*)(Kg + bhBase + (size_t)rr0 * 64 + c8 * 8);
    bf16x8 kr1 = *(const bf16x8*)(Kg + bhBase + (size_t)rr1 * 64 + c8 * 8);
    bf16x8 vr0 = *(const bf16x8*)(Vt + bhBase + (size_t)rr0 * 2048 + c8 * 8);
    bf16x8 vr1 = *(const bf16x8*)(Vt + bhBase + (size_t)rr1 * 2048 + c8 * 8);
    *(bf16x8*)((char*)Ks[0] + koff0) = kr0;
    *(bf16x8*)((char*)Ks[0] + koff1) = kr1;
    *(bf16x8*)((char*)Vs[0] + koff0) = vr0;
    *(bf16x8*)((char*)Vs[0] + koff1) = vr1;
    __syncthreads();

    float m2[4], lrow[4];
    f32x4 accO[4] = {};
    #pragma unroll
    for (int r = 0; r < 4; ++r) { m2[r] = -1e30f; lrow[r] = 0.0f; }

    constexpr float CSC = 0.18033688011f;   // 0.125 * log2(e)

    for (int t = 0; t <= qt; ++t) {
        const int cur = t & 1;
        const bool pf = (t < qt);

        if (pf) {   // issue next-tile loads early; consumed after compute
            const size_t kb = bhBase + (size_t)(t + 1) * 64 * 64;
            kr0 = *(const bf16x8*)(Kg + kb + (size_t)rr0 * 64 + c8 * 8);
            kr1 = *(const bf16x8*)(Kg + kb + (size_t)rr1 * 64 + c8 * 8);
            const size_t vb = bhBase + (size_t)(t + 1) * 64;
            vr0 = *(const bf16x8*)(Vt + vb + (size_t)rr0 * 2048 + c8 * 8);
            vr1 = *(const bf16x8*)(Vt + vb + (size_t)rr1 * 2048 + c8 * 8);
        }

        // S = Q K^T
        f32x4 sf[4];
        #pragma unroll
        for (int n = 0; n < 4; ++n) {
            int row = n * 16 + lq;
            f32x4 acc = {};
            #pragma unroll
            for (int ks = 0; ks < 2; ++ks) {
                int off = row * 128 + (((ks * 64) + lk * 16) ^ ((row & 7) << 4));
                bf16x8 kb_ = *(const bf16x8*)((const char*)Ks[cur] + off);
                acc = __builtin_amdgcn_mfma_f32_16x16x32_bf16(qa[ks], kb_, acc, 0, 0, 0);
            }
            sf[n] = acc;
        }

        // scale to log2 domain (+ causal mask on diagonal tile)
        if (t == qt) {
            #pragma unroll
            for (int n = 0; n < 4; ++n)
                #pragma unroll
                for (int r = 0; r < 4; ++r) {
                    float s = sf[n][r] * CSC;
                    sf[n][r] = ((n * 16 + lq) > (w * 16 + lk * 4 + r)) ? -1e30f : s;
                }
        } else {
            #pragma unroll
            for (int n = 0; n < 4; ++n)
                #pragma unroll
                for (int r = 0; r < 4; ++r) sf[n][r] *= CSC;
        }

        // row maxima (16 lanes along lq hold the 64 kv cols)
        float pm[4];
        #pragma unroll
        for (int r = 0; r < 4; ++r) {
            float p = fmaxf(fmaxf(sf[0][r], sf[1][r]), fmaxf(sf[2][r], sf[3][r]));
            p = fmaxf(p, __shfl_xor(p, 1));
            p = fmaxf(p, __shfl_xor(p, 2));
            p = fmaxf(p, __shfl_xor(p, 4));
            p = fmaxf(p, __shfl_xor(p, 8));
            pm[r] = p;
        }

        // defer-max: only rescale when some row grew past THR
        bool ok = (pm[0] <= m2[0] + 11.5f) && (pm[1] <= m2[1] + 11.5f) &&
                  (pm[2] <= m2[2] + 11.5f) && (pm[3] <= m2[3] + 11.5f);
        if (!__all(ok)) {
            #pragma unroll
            for (int r = 0; r < 4; ++r) {
                float mn = fmaxf(m2[r], pm[r]);
                float al = exp2f(m2[r] - mn);
                m2[r] = mn;
                lrow[r] *= al;
                #pragma unroll
                for (int n = 0; n < 4; ++n) accO[n][r] *= al;
            }
        }

        // P = exp2(s - m), row sums
        float rs[4] = {};
        #pragma unroll
        for (int n = 0; n < 4; ++n)
            #pragma unroll
            for (int r = 0; r < 4; ++r) {
                float p = exp2f(sf[n][r] - m2[r]);
                sf[n][r] = p;
                rs[r] += p;
            }
        #pragma unroll
        for (int r = 0; r < 4; ++r) {
            float s = rs[r];
            s += __shfl_xor(s, 1);
            s += __shfl_xor(s, 2);
            s += __shfl_xor(s, 4);
            s += __shfl_xor(s, 8);
            lrow[r] += s;
        }

        // P -> per-wave swizzled LDS (bf16), transposing for the PV A-operand
        #pragma unroll
        for (int r = 0; r < 4; ++r) {
            int prow = lk * 4 + r;
            #pragma unroll
            for (int n = 0; n < 4; ++n) {
                int off = prow * 128 + (((n * 16 + lq) * 2) ^ ((prow & 7) << 4));
                *(ushort_t*)((char*)Ps[w] + off) = f2bf(sf[n][r]);
            }
        }
        asm volatile("s_waitcnt lgkmcnt(0)" ::: "memory");

        // O += P V
        #pragma unroll
        for (int ks = 0; ks < 2; ++ks) {
            int poff = lq * 128 + (((ks * 64) + lk * 16) ^ ((lq & 7) << 4));
            bf16x8 pa = *(const bf16x8*)((const char*)Ps[w] + poff);
            #pragma unroll
            for (int n = 0; n < 4; ++n) {
                int row = n * 16 + lq;
                int voff = row * 128 + (((ks * 64) + lk * 16) ^ ((row & 7) << 4));
                bf16x8 vb_ = *(const bf16x8*)((const char*)Vs[cur] + voff);
                accO[n] = __builtin_amdgcn_mfma_f32_16x16x32_bf16(pa, vb_, accO[n], 0, 0, 0);
            }
        }

        if (pf) {   // drain prefetch into the other buffer; single barrier
            *(bf16x8*)((char*)Ks[cur ^ 1] + koff0) = kr0;
            *(bf16x8*)((char*)Ks[cur ^ 1] + koff1) = kr1;
            *(bf16x8*)((char*)Vs[cur ^ 1] + koff0) = vr0;
            *(bf16x8*)((char*)Vs[cur ^ 1] + koff1) = vr1;
            __syncthreads();
        }
    }

    const int b_ = bh >> 4, h = bh & 15;
    #pragma unroll
    for (int r = 0; r < 4; ++r) {
        float inv = 1.0f / lrow[r];
        int s = q0 + w * 16 + lk * 4 + r;
        size_t base = ((size_t)b_ * 2048 + s) * 1024 + h * 64;
        #pragma unroll
        for (int n = 0; n < 4; ++n)
            O[base + n * 16 + lq] = f2bf(accO[n][r] * inv);
    }
}

} // anonymous namespace

extern "C" void kernel_launch(void* const* d_in, const int* in_sizes, int n_in,
                              void* d_out, int out_size, void* d_ws, size_t ws_size,
                              hipStream_t stream)
{
    const float* x  = (const float*)d_in[0];
    const float* Wq = (const float*)d_in[1];
    const float* Wk = (const float*)d_in[2];
    const float* Wv = (const float*)d_in[3];
    const float* Wo = (const float*)d_in[4];

    ushort_t* xb  = (ushort_t*)d_ws;              // [4096][1024]        4M elems
    ushort_t* Wt  = xb  + 4194304;                // [3072][1024] (B^T)  3M elems
    ushort_t* Wot = Wt  + 3145728;                // [1024][1024] (B^T)  1M elems
    ushort_t* Qb  = Wot + 1048576;                // [32][2048][64]      4M elems
    ushort_t* Kb  = Qb  + 4194304;                // [32][2048][64]      4M elems
    ushort_t* Vtb = Kb  + 4194304;                // [32][64][2048]      4M elems
    ushort_t* Ob  = Vtb + 4194304;                // [4096][1024]        4M elems
    float*    tbl = (float*)(Ob + 4194304);       // [2048][32][2] fp32  512 KB

    conv_kernel<<<2048, 256, 0, stream>>>(x, xb);
    rope_table_kernel<<<256, 256, 0, stream>>>(tbl);
    tconv_kernel<<<dim3(16, 1, 16), 256, 0, stream>>>(Wq, Wt,           1024, 64, 65536, 65536);
    tconv_kernel<<<dim3(16, 1, 16), 256, 0, stream>>>(Wk, Wt + 1048576, 1024, 64, 65536, 65536);
    tconv_kernel<<<dim3(16, 1, 16), 256, 0, stream>>>(Wv, Wt + 2097152, 1024, 64, 65536, 65536);
    tconv_kernel<<<dim3(16, 16, 1), 256, 0, stream>>>(Wo, Wot,          1024, 1024, 0, 0);

    gemm_kernel<0><<<dim3(32, 24), 256, 0, stream>>>(xb, Wt, Qb, Kb, Vtb, nullptr, 1024);

    rope_kernel<<<4096, 256, 0, stream>>>(Qb, tbl);
    rope_kernel<<<4096, 256, 0, stream>>>(Kb, tbl);

    attn_kernel<<<1024, 256, 0, stream>>>(Qb, Kb, Vtb, Ob);

    gemm_kernel<1><<<dim3(32, 8), 256, 0, stream>>>(Ob, Wot, nullptr, nullptr, nullptr,
                                                    (float*)d_out, 1024);
}

// Round 6
// 177.510 us; speedup vs baseline: 6.0271x; 1.0569x over previous
//
#include <hip/hip_runtime.h>
#include <math.h>

typedef __attribute__((ext_vector_type(8))) short bf16x8;
typedef __attribute__((ext_vector_type(4))) float f32x4;
typedef __attribute__((ext_vector_type(16))) float f32x16;
typedef __attribute__((ext_vector_type(4))) unsigned int uint32x4;
typedef __attribute__((ext_vector_type(2))) unsigned int uint32x2;
typedef unsigned short ushort_t;
typedef unsigned int uint_t;

typedef const void __attribute__((address_space(1)))* gas_ptr;
typedef void __attribute__((address_space(3)))* las_ptr;

namespace {

constexpr int S_  = 2048;
constexpr int D_  = 1024;
constexpr float CSC = 0.18033688011f;   // 0.125 * log2(e): score scale in log2 domain

__device__ inline ushort_t f2bf(float f) {
    uint_t u = __builtin_bit_cast(uint_t, f);
    u += 0x7FFFu + ((u >> 16) & 1u);
    return (ushort_t)(u >> 16);
}
__device__ inline float bf2f(ushort_t b) {
    uint_t u = ((uint_t)b) << 16;
    return __builtin_bit_cast(float, u);
}
__device__ inline uint_t cvtpk(float lo, float hi) {
    uint_t r;
    asm("v_cvt_pk_bf16_f32 %0, %1, %2" : "=v"(r) : "v"(lo), "v"(hi));
    return r;
}
// v_permlane32_swap_b32 semantics (derived from m214's verified recipe):
//   new D.lanes[32:63] = old S.lanes[0:31];  new S.lanes[0:31] = old D.lanes[32:63]
// i.e. swap D's HIGH half with S's LOW half. Both outputs are usable frag words.
__device__ inline void plswap(uint_t& d, uint_t& s) {
    uint32x2 r = __builtin_amdgcn_permlane32_swap(d, s, false, false);
    d = r[0];
    s = r[1];
}

// ---------------------------------------------------------------------------
// convert fp32 -> bf16, 8 elems/thread
// ---------------------------------------------------------------------------
__global__ __launch_bounds__(256)
void conv_kernel(const float* __restrict__ src, ushort_t* __restrict__ dst)
{
    int i = blockIdx.x * 256 + threadIdx.x;
    float4 a = ((const float4*)src)[i * 2];
    float4 b = ((const float4*)src)[i * 2 + 1];
    uint_t u0 = (uint_t)f2bf(a.x) | ((uint_t)f2bf(a.y) << 16);
    uint_t u1 = (uint_t)f2bf(a.z) | ((uint_t)f2bf(a.w) << 16);
    uint_t u2 = (uint_t)f2bf(b.x) | ((uint_t)f2bf(b.y) << 16);
    uint_t u3 = (uint_t)f2bf(b.z) | ((uint_t)f2bf(b.w) << 16);
    ((uint4*)dst)[i] = make_uint4(u0, u1, u2, u3);
}

// ---------------------------------------------------------------------------
// transpose + convert: src fp32 [R][C] -> dst bf16 [C][R], 64x64 tiles.
// ---------------------------------------------------------------------------
__global__ __launch_bounds__(256)
void tconv_kernel(const float* __restrict__ src, ushort_t* __restrict__ dst,
                  int R, int C, long zss, long zds)
{
    __shared__ float Tl[64][65];
    src += (size_t)blockIdx.z * zss;
    dst += (size_t)blockIdx.z * zds;
    const int r0 = blockIdx.x * 64, c0 = blockIdx.y * 64;
    const int tid = threadIdx.x;
    #pragma unroll
    for (int l = 0; l < 4; ++l) {
        int i = tid + l * 256;
        int row = i >> 4, col = (i & 15) * 4;
        float4 v = *(const float4*)(src + (size_t)(r0 + row) * C + c0 + col);
        Tl[row][col] = v.x; Tl[row][col + 1] = v.y;
        Tl[row][col + 2] = v.z; Tl[row][col + 3] = v.w;
    }
    __syncthreads();
    #pragma unroll
    for (int l = 0; l < 4; ++l) {
        int i = tid + l * 256;
        int cc = i >> 4, rr = (i & 15) * 4;
        uint_t lo = (uint_t)f2bf(Tl[rr][cc])     | ((uint_t)f2bf(Tl[rr + 1][cc]) << 16);
        uint_t hi = (uint_t)f2bf(Tl[rr + 2][cc]) | ((uint_t)f2bf(Tl[rr + 3][cc]) << 16);
        *(uint2*)(dst + (size_t)(c0 + cc) * R + r0 + rr) = make_uint2(lo, hi);
    }
}

// ---------------------------------------------------------------------------
// RoPE cos/sin table: tbl[s][p] = (cos, sin) of s * theta^(-p/32), 2048 x 32
// ---------------------------------------------------------------------------
__global__ __launch_bounds__(256)
void rope_table_kernel(float* __restrict__ tbl)
{
    int i = blockIdx.x * 256 + threadIdx.x;     // 65536 entries
    int s = i >> 5, p = i & 31;
    float inv = powf(10000.0f, -(float)p * (1.0f / 32.0f));
    float sn, cs;
    sincosf((float)s * inv, &sn, &cs);
    ((float2*)tbl)[i] = make_float2(cs, sn);
}

// ---------------------------------------------------------------------------
// RoPE in-place on bf16 [BH][S][DK=64]; 4 elems (2 pairs) / thread, table-read.
// ---------------------------------------------------------------------------
__global__ __launch_bounds__(256)
void rope_kernel(ushort_t* __restrict__ T, const float* __restrict__ tbl)
{
    int i = blockIdx.x * 256 + threadIdx.x;
    int flat = i * 4;
    int dk = flat & 63;
    int s  = (flat >> 6) & 2047;
    int p0 = dk >> 1;                            // even
    float4 cssn = *(const float4*)(tbl + ((size_t)s * 32 + p0) * 2);
    uint2 lv = *(uint2*)(T + flat);
    float e0 = bf2f((ushort_t)(lv.x & 0xffff));
    float o0 = bf2f((ushort_t)(lv.x >> 16));
    float e1 = bf2f((ushort_t)(lv.y & 0xffff));
    float o1 = bf2f((ushort_t)(lv.y >> 16));
    float r0 = e0 * cssn.x - o0 * cssn.y;
    float r1 = o0 * cssn.x + e0 * cssn.y;
    float r2 = e1 * cssn.z - o1 * cssn.w;
    float r3 = o1 * cssn.z + e1 * cssn.w;
    uint_t w0 = (uint_t)f2bf(r0) | ((uint_t)f2bf(r1) << 16);
    uint_t w1 = (uint_t)f2bf(r2) | ((uint_t)f2bf(r3) << 16);
    *(uint2*)(T + flat) = make_uint2(w0, w1);
}

// ---------------------------------------------------------------------------
// m97-style bf16 MFMA GEMM: C[M][N] = A[M][K] * Bt[N][K]^T
// MODE 0: QKV epilogue -> Q (pre-scaled by CSC), K as [bh][s][64] bf16,
//         V as [bh][64][s] bf16 (transposed)
// MODE 1: fp32 epilogue -> Co[M][N]
// ---------------------------------------------------------------------------
template<int MODE>
__global__ __launch_bounds__(256)
void gemm_kernel(const ushort_t* __restrict__ A, const ushort_t* __restrict__ Bt,
                 ushort_t* __restrict__ Qo, ushort_t* __restrict__ Ko,
                 ushort_t* __restrict__ Vto, float* __restrict__ Co, int K)
{
    __shared__ ushort_t As[128 * 32];
    __shared__ ushort_t Bs[128 * 32];

    const int tid  = threadIdx.x;
    const int w    = tid >> 6, lane = tid & 63;
    const int lq   = lane & 15, lk = lane >> 4;
    const int wr   = w >> 1, wc = w & 1;
    const int m0   = blockIdx.x * 128;
    const int n0   = blockIdx.y * 128;

    f32x4 acc[4][4] = {};

    for (int k0 = 0; k0 < K; k0 += 32) {
        #pragma unroll
        for (int i = 0; i < 2; ++i) {
            int c   = i * 256 + tid;
            int row = c >> 2, c4 = c & 3;
            const ushort_t* ga = A  + (size_t)(m0 + row) * K + k0 + c4 * 8;
            const ushort_t* gb = Bt + (size_t)(n0 + row) * K + k0 + c4 * 8;
            int base = (i * 256 + w * 64) * 16;
            __builtin_amdgcn_global_load_lds((gas_ptr)ga, (las_ptr)((char*)As + base), 16, 0, 0);
            __builtin_amdgcn_global_load_lds((gas_ptr)gb, (las_ptr)((char*)Bs + base), 16, 0, 0);
        }
        __syncthreads();

        bf16x8 a[4], b[4];
        #pragma unroll
        for (int m = 0; m < 4; ++m)
            a[m] = *(const bf16x8*)((const char*)As + (wr * 64 + m * 16 + lq) * 64 + lk * 16);
        #pragma unroll
        for (int n = 0; n < 4; ++n)
            b[n] = *(const bf16x8*)((const char*)Bs + (wc * 64 + n * 16 + lq) * 64 + lk * 16);
        #pragma unroll
        for (int m = 0; m < 4; ++m)
            #pragma unroll
            for (int n = 0; n < 4; ++n)
                acc[m][n] = __builtin_amdgcn_mfma_f32_16x16x32_bf16(a[m], b[n], acc[m][n], 0, 0, 0);
        __syncthreads();
    }

    if (MODE == 0) {
        const int sel = n0 >> 10;
        ushort_t* dst = (sel == 0) ? Qo : (sel == 1) ? Ko : Vto;
        const float sc = (sel == 0) ? CSC : 1.0f;
        #pragma unroll
        for (int m = 0; m < 4; ++m) {
            #pragma unroll
            for (int r = 0; r < 4; ++r) {
                int mg = m0 + wr * 64 + m * 16 + lk * 4 + r;
                int b_ = mg >> 11, s = mg & 2047;
                #pragma unroll
                for (int n = 0; n < 4; ++n) {
                    int ng = n0 + wc * 64 + n * 16 + lq;
                    int h = (ng >> 6) & 15, dk = ng & 63;
                    ushort_t v = f2bf(acc[m][n][r] * sc);
                    if (sel < 2)
                        dst[(((size_t)b_ * 16 + h) * 2048 + s) * 64 + dk] = v;
                    else
                        dst[(((size_t)b_ * 16 + h) * 64 + dk) * 2048 + s] = v;
                }
            }
        }
    } else {
        #pragma unroll
        for (int m = 0; m < 4; ++m) {
            #pragma unroll
            for (int r = 0; r < 4; ++r) {
                int mg = m0 + wr * 64 + m * 16 + lk * 4 + r;
                #pragma unroll
                for (int n = 0; n < 4; ++n) {
                    int ng = n0 + wc * 64 + n * 16 + lq;
                    Co[(size_t)mg * D_ + ng] = acc[m][n][r];
                }
            }
        }
    }
}

// ---------------------------------------------------------------------------
// MFMA causal flash attention, swapped-QK^T 32x32x16 structure (m214-style).
// grid 1024 (zigzag), 128 threads = 2 waves; wave w owns q-rows
// [64*qt + 32w, +32). Each lane owns ONE q row (q = lane&31); softmax is
// in-lane + one shfl_xor(32) per 32-kv tile. P goes to the PV A-operand
// in-register via cvt_pk + permlane32_swap (no LDS round-trip).
// K [64kv][64dk] and V^T [64dk][64kv] staged via global_load_lds with
// pre-swizzled source (16B-slot XOR), double-buffered, counted vmcnt.
// Tile = 512 x 16B slots; 128 threads -> 4 staging iters, 8 loads/wave/stage.
// ---------------------------------------------------------------------------
__global__ __launch_bounds__(128)
void attn_kernel(const ushort_t* __restrict__ Q, const ushort_t* __restrict__ Kg,
                 const ushort_t* __restrict__ Vt, ushort_t* __restrict__ O)
{
    __shared__ ushort_t Ks[2][64 * 64];
    __shared__ ushort_t Vs[2][64 * 64];

    const int bid = blockIdx.x;
    const int g = bid >> 8, ii = bid & 255;
    const int r8 = ii >> 3;
    const int qt = (g & 1) ? r8 : 31 - r8;
    const int bh = (ii & 7) | (g << 3);

    const int tid = threadIdx.x;                 // 0..127
    const int w = tid >> 6, lane = tid & 63;
    const int lq = lane & 31, hi = lane >> 5;
    const size_t bhBase = (size_t)bh * S_ * 64;

    // Q fragments (B-operand): lane holds Q[q0w+lq][c*16 + hi*8 .. +8]
    bf16x8 qf[4];
    {
        const ushort_t* qp = Q + bhBase + (size_t)(qt * 64 + w * 32 + lq) * 64 + hi * 8;
        qf[0] = *(const bf16x8*)(qp);
        qf[1] = *(const bf16x8*)(qp + 16);
        qf[2] = *(const bf16x8*)(qp + 32);
        qf[3] = *(const bf16x8*)(qp + 48);
    }

    // stage tile t into buffer buf: linear LDS dest, source pre-swizzled so a
    // swizzled read (slot ^ (row&7)) sees the natural layout (rule 21c).
    // 512 slots of 16B per tensor; 4 iters x 128 threads.
    auto stage = [&](int buf, int t) {
        #pragma unroll
        for (int i = 0; i < 4; ++i) {
            int slot = i * 128 + w * 64 + lane;
            int rr = slot >> 3, c8 = slot & 7;
            int c8s = c8 ^ (rr & 7);
            const ushort_t* gk = Kg + bhBase + (size_t)(t * 64 + rr) * 64 + c8s * 8;
            const ushort_t* gv = Vt + bhBase + (size_t)rr * 2048 + t * 64 + c8s * 8;
            int ldsb = (i * 128 + w * 64) * 16;
            __builtin_amdgcn_global_load_lds((gas_ptr)gk, (las_ptr)((char*)Ks[buf] + ldsb), 16, 0, 0);
            __builtin_amdgcn_global_load_lds((gas_ptr)gv, (las_ptr)((char*)Vs[buf] + ldsb), 16, 0, 0);
        }
    };

    float m = -1e30f, l = 0.0f;
    f32x16 oacc[2] = {};

    stage(0, 0);

    for (int t = 0; t <= qt; ++t) {
        const int cur = t & 1;
        if (t < qt) {
            stage(cur ^ 1, t + 1);
            asm volatile("s_waitcnt vmcnt(8)" ::: "memory");   // drain current tile's 8
        } else {
            asm volatile("s_waitcnt vmcnt(0)" ::: "memory");
        }
        __builtin_amdgcn_s_barrier();
        asm volatile("" ::: "memory");

        const int nst = (t == qt && w == 0) ? 1 : 2;   // wave0 skips fully-masked half
        #pragma unroll 2
        for (int st = 0; st < nst; ++st) {
            // S^T[kv=32][q=32] = K-frag * Q-frag over k=64
            f32x16 sacc = {};
            #pragma unroll
            for (int c = 0; c < 4; ++c) {
                int row = st * 32 + lq;              // kv row in tile
                int koff = row * 128 + ((c * 32 + hi * 16) ^ ((row & 7) << 4));
                bf16x8 kf = *(const bf16x8*)((const char*)Ks[cur] + koff);
                sacc = __builtin_amdgcn_mfma_f32_32x32x16_bf16(kf, qf[c], sacc, 0, 0, 0);
            }

            if (t == qt && st == w) {                // diagonal 32x32 sub-tile
                #pragma unroll
                for (int idx = 0; idx < 16; ++idx) {
                    int kvl = (idx & 3) + 8 * (idx >> 2) + 4 * hi;
                    if (kvl > lq) sacc[idx] = -1e30f;
                }
            }

            // row max: 15 in-lane + one cross-half exchange
            float pm = sacc[0];
            #pragma unroll
            for (int idx = 1; idx < 16; ++idx) pm = fmaxf(pm, sacc[idx]);
            pm = fmaxf(pm, __shfl_xor(pm, 32));

            if (__any(pm > m + 11.5f)) {             // defer-max (log2 domain)
                float mn = fmaxf(m, pm);
                float al = exp2f(m - mn);
                m = mn;
                l *= al;
                #pragma unroll
                for (int idx = 0; idx < 16; ++idx) { oacc[0][idx] *= al; oacc[1][idx] *= al; }
            }

            // P = exp2(S - m); l accumulates own half only (halves see equal alphas)
            float p[16];
            #pragma unroll
            for (int idx = 0; idx < 16; ++idx) {
                float v = exp2f(sacc[idx] - m);
                p[idx] = v;
                l += v;
            }

            // PV: O^T[dk][q] += V^T-frag * P^T-frag, kv chunks of 16.
            // Lane holds P[q=lq][kv] at kv=(idx&3)+8*(idx>>2)+4hi; chunk c2 uses
            // p[8c2..8c2+7]. Build B-frag words: w_j.lo = kv(2j,2j+1),
            // w_j.hi = kv(8+2j,9+2j) via permlane32_swap (D.hi <-> S.lo):
            //   swap(a0=pk(p0,p1), a2=pk(p4,p5)) -> {w0, w2}
            //   swap(a1=pk(p2,p3), a3=pk(p6,p7)) -> {w1, w3}
            #pragma unroll
            for (int c2 = 0; c2 < 2; ++c2) {
                uint_t w0 = cvtpk(p[8 * c2 + 0], p[8 * c2 + 1]);
                uint_t w1 = cvtpk(p[8 * c2 + 2], p[8 * c2 + 3]);
                uint_t w2 = cvtpk(p[8 * c2 + 4], p[8 * c2 + 5]);
                uint_t w3 = cvtpk(p[8 * c2 + 6], p[8 * c2 + 7]);
                plswap(w0, w2);                      // w0.hi<-w2.lo, w2.lo<-w0.hi
                plswap(w1, w3);
                uint32x4 pw; pw[0] = w0; pw[1] = w1; pw[2] = w2; pw[3] = w3;
                bf16x8 pb = __builtin_bit_cast(bf16x8, pw);
                #pragma unroll
                for (int d2 = 0; d2 < 2; ++d2) {
                    int row = d2 * 32 + lq;          // dk row
                    int voff = row * 128 + ((st * 64 + c2 * 32 + hi * 16) ^ ((row & 7) << 4));
                    bf16x8 vf = *(const bf16x8*)((const char*)Vs[cur] + voff);
                    oacc[d2] = __builtin_amdgcn_mfma_f32_32x32x16_bf16(vf, pb, oacc[d2], 0, 0, 0);
                }
            }
        }
        asm volatile("" ::: "memory");
        __builtin_amdgcn_s_barrier();                // all reads of buf[cur] done
        asm volatile("" ::: "memory");
    }

    // epilogue: combine halves of l, normalize, write O[b][s][h*64+dk]
    l += __shfl_xor(l, 32);
    float inv = 1.0f / l;
    const int b_ = bh >> 4, h = bh & 15;
    const int s = qt * 64 + w * 32 + lq;
    ushort_t* ob = O + ((size_t)b_ * 2048 + s) * 1024 + h * 64;
    #pragma unroll
    for (int d2 = 0; d2 < 2; ++d2)
        #pragma unroll
        for (int gg = 0; gg < 4; ++gg) {
            int dk0 = d2 * 32 + 8 * gg + 4 * hi;
            uint2 pkv;
            pkv.x = cvtpk(oacc[d2][gg * 4 + 0] * inv, oacc[d2][gg * 4 + 1] * inv);
            pkv.y = cvtpk(oacc[d2][gg * 4 + 2] * inv, oacc[d2][gg * 4 + 3] * inv);
            *(uint2*)(ob + dk0) = pkv;
        }
}

} // anonymous namespace

extern "C" void kernel_launch(void* const* d_in, const int* in_sizes, int n_in,
                              void* d_out, int out_size, void* d_ws, size_t ws_size,
                              hipStream_t stream)
{
    const float* x  = (const float*)d_in[0];
    const float* Wq = (const float*)d_in[1];
    const float* Wk = (const float*)d_in[2];
    const float* Wv = (const float*)d_in[3];
    const float* Wo = (const float*)d_in[4];

    ushort_t* xb  = (ushort_t*)d_ws;              // [4096][1024]        4M elems
    ushort_t* Wt  = xb  + 4194304;                // [3072][1024] (B^T)  3M elems
    ushort_t* Wot = Wt  + 3145728;                // [1024][1024] (B^T)  1M elems
    ushort_t* Qb  = Wot + 1048576;                // [32][2048][64]      4M elems
    ushort_t* Kb  = Qb  + 4194304;                // [32][2048][64]      4M elems
    ushort_t* Vtb = Kb  + 4194304;                // [32][64][2048]      4M elems
    ushort_t* Ob  = Vtb + 4194304;                // [4096][1024]        4M elems
    float*    tbl = (float*)(Ob + 4194304);       // [2048][32][2] fp32  512 KB

    conv_kernel<<<2048, 256, 0, stream>>>(x, xb);
    rope_table_kernel<<<256, 256, 0, stream>>>(tbl);
    tconv_kernel<<<dim3(16, 1, 16), 256, 0, stream>>>(Wq, Wt,           1024, 64, 65536, 65536);
    tconv_kernel<<<dim3(16, 1, 16), 256, 0, stream>>>(Wk, Wt + 1048576, 1024, 64, 65536, 65536);
    tconv_kernel<<<dim3(16, 1, 16), 256, 0, stream>>>(Wv, Wt + 2097152, 1024, 64, 65536, 65536);
    tconv_kernel<<<dim3(16, 16, 1), 256, 0, stream>>>(Wo, Wot,          1024, 1024, 0, 0);

    gemm_kernel<0><<<dim3(32, 24), 256, 0, stream>>>(xb, Wt, Qb, Kb, Vtb, nullptr, 1024);

    rope_kernel<<<4096, 256, 0, stream>>>(Qb, tbl);
    rope_kernel<<<4096, 256, 0, stream>>>(Kb, tbl);

    attn_kernel<<<1024, 128, 0, stream>>>(Qb, Kb, Vtb, Ob);

    gemm_kernel<1><<<dim3(32, 8), 256, 0, stream>>>(Ob, Wot, nullptr, nullptr, nullptr,
                                                    (float*)d_out, 1024);
}

// Round 7
// 152.203 us; speedup vs baseline: 7.0292x; 1.1663x over previous
//
#include <hip/hip_runtime.h>
#include <math.h>

typedef __attribute__((ext_vector_type(8))) short bf16x8;
typedef __attribute__((ext_vector_type(4))) float f32x4;
typedef __attribute__((ext_vector_type(16))) float f32x16;
typedef __attribute__((ext_vector_type(4))) unsigned int uint32x4;
typedef __attribute__((ext_vector_type(2))) unsigned int uint32x2;
typedef unsigned short ushort_t;
typedef unsigned int uint_t;

typedef const void __attribute__((address_space(1)))* gas_ptr;
typedef void __attribute__((address_space(3)))* las_ptr;

namespace {

constexpr int S_  = 2048;
constexpr int D_  = 1024;
constexpr float CSC = 0.18033688011f;   // 0.125 * log2(e): score scale in log2 domain

__device__ inline ushort_t f2bf(float f) {
    uint_t u = __builtin_bit_cast(uint_t, f);
    u += 0x7FFFu + ((u >> 16) & 1u);
    return (ushort_t)(u >> 16);
}
__device__ inline float bf2f(ushort_t b) {
    uint_t u = ((uint_t)b) << 16;
    return __builtin_bit_cast(float, u);
}
__device__ inline uint_t cvtpk(float lo, float hi) {
    uint_t r;
    asm("v_cvt_pk_bf16_f32 %0, %1, %2" : "=v"(r) : "v"(lo), "v"(hi));
    return r;
}
// permlane32_swap: swaps D.hi-half-lanes with S.lo-half-lanes (verified R6).
__device__ inline void plswap(uint_t& d, uint_t& s) {
    uint32x2 r = __builtin_amdgcn_permlane32_swap(d, s, false, false);
    d = r[0];
    s = r[1];
}

// ---------------------------------------------------------------------------
// convert fp32 -> bf16, 8 elems/thread
// ---------------------------------------------------------------------------
__global__ __launch_bounds__(256)
void conv_kernel(const float* __restrict__ src, ushort_t* __restrict__ dst)
{
    int i = blockIdx.x * 256 + threadIdx.x;
    float4 a = ((const float4*)src)[i * 2];
    float4 b = ((const float4*)src)[i * 2 + 1];
    uint_t u0 = (uint_t)f2bf(a.x) | ((uint_t)f2bf(a.y) << 16);
    uint_t u1 = (uint_t)f2bf(a.z) | ((uint_t)f2bf(a.w) << 16);
    uint_t u2 = (uint_t)f2bf(b.x) | ((uint_t)f2bf(b.y) << 16);
    uint_t u3 = (uint_t)f2bf(b.z) | ((uint_t)f2bf(b.w) << 16);
    ((uint4*)dst)[i] = make_uint4(u0, u1, u2, u3);
}

// ---------------------------------------------------------------------------
// transpose + convert: src fp32 [R][C] -> dst bf16 [C][R], 64x64 tiles.
// ---------------------------------------------------------------------------
__global__ __launch_bounds__(256)
void tconv_kernel(const float* __restrict__ src, ushort_t* __restrict__ dst,
                  int R, int C, long zss, long zds)
{
    __shared__ float Tl[64][65];
    src += (size_t)blockIdx.z * zss;
    dst += (size_t)blockIdx.z * zds;
    const int r0 = blockIdx.x * 64, c0 = blockIdx.y * 64;
    const int tid = threadIdx.x;
    #pragma unroll
    for (int l = 0; l < 4; ++l) {
        int i = tid + l * 256;
        int row = i >> 4, col = (i & 15) * 4;
        float4 v = *(const float4*)(src + (size_t)(r0 + row) * C + c0 + col);
        Tl[row][col] = v.x; Tl[row][col + 1] = v.y;
        Tl[row][col + 2] = v.z; Tl[row][col + 3] = v.w;
    }
    __syncthreads();
    #pragma unroll
    for (int l = 0; l < 4; ++l) {
        int i = tid + l * 256;
        int cc = i >> 4, rr = (i & 15) * 4;
        uint_t lo = (uint_t)f2bf(Tl[rr][cc])     | ((uint_t)f2bf(Tl[rr + 1][cc]) << 16);
        uint_t hi = (uint_t)f2bf(Tl[rr + 2][cc]) | ((uint_t)f2bf(Tl[rr + 3][cc]) << 16);
        *(uint2*)(dst + (size_t)(c0 + cc) * R + r0 + rr) = make_uint2(lo, hi);
    }
}

// ---------------------------------------------------------------------------
// RoPE cos/sin table: tbl[s][p] = (cos, sin) of s * theta^(-p/32), 2048 x 32
// ---------------------------------------------------------------------------
__global__ __launch_bounds__(256)
void rope_table_kernel(float* __restrict__ tbl)
{
    int i = blockIdx.x * 256 + threadIdx.x;     // 65536 entries
    int s = i >> 5, p = i & 31;
    float inv = powf(10000.0f, -(float)p * (1.0f / 32.0f));
    float sn, cs;
    sincosf((float)s * inv, &sn, &cs);
    ((float2*)tbl)[i] = make_float2(cs, sn);
}

// ---------------------------------------------------------------------------
// m97-style bf16 MFMA GEMM: C[M][N] = A[M][K] * Bt[N][K]^T
// MODE 0: QKV epilogue: Q (pre-scaled CSC) and K get RoPE applied IN-EPILOGUE
//         (pair partner via shfl_xor(1), cos/sin from table); V transposed.
// MODE 1: fp32 epilogue -> Co[M][N]
// ---------------------------------------------------------------------------
template<int MODE>
__global__ __launch_bounds__(256)
void gemm_kernel(const ushort_t* __restrict__ A, const ushort_t* __restrict__ Bt,
                 ushort_t* __restrict__ Qo, ushort_t* __restrict__ Ko,
                 ushort_t* __restrict__ Vto, float* __restrict__ Co,
                 const float* __restrict__ tbl, int K)
{
    __shared__ ushort_t As[128 * 32];
    __shared__ ushort_t Bs[128 * 32];

    const int tid  = threadIdx.x;
    const int w    = tid >> 6, lane = tid & 63;
    const int lq   = lane & 15, lk = lane >> 4;
    const int wr   = w >> 1, wc = w & 1;
    const int m0   = blockIdx.x * 128;
    const int n0   = blockIdx.y * 128;

    f32x4 acc[4][4] = {};

    for (int k0 = 0; k0 < K; k0 += 32) {
        #pragma unroll
        for (int i = 0; i < 2; ++i) {
            int c   = i * 256 + tid;
            int row = c >> 2, c4 = c & 3;
            const ushort_t* ga = A  + (size_t)(m0 + row) * K + k0 + c4 * 8;
            const ushort_t* gb = Bt + (size_t)(n0 + row) * K + k0 + c4 * 8;
            int base = (i * 256 + w * 64) * 16;
            __builtin_amdgcn_global_load_lds((gas_ptr)ga, (las_ptr)((char*)As + base), 16, 0, 0);
            __builtin_amdgcn_global_load_lds((gas_ptr)gb, (las_ptr)((char*)Bs + base), 16, 0, 0);
        }
        __syncthreads();

        bf16x8 a[4], b[4];
        #pragma unroll
        for (int m = 0; m < 4; ++m)
            a[m] = *(const bf16x8*)((const char*)As + (wr * 64 + m * 16 + lq) * 64 + lk * 16);
        #pragma unroll
        for (int n = 0; n < 4; ++n)
            b[n] = *(const bf16x8*)((const char*)Bs + (wc * 64 + n * 16 + lq) * 64 + lk * 16);
        #pragma unroll
        for (int m = 0; m < 4; ++m)
            #pragma unroll
            for (int n = 0; n < 4; ++n)
                acc[m][n] = __builtin_amdgcn_mfma_f32_16x16x32_bf16(a[m], b[n], acc[m][n], 0, 0, 0);
        __syncthreads();
    }

    if (MODE == 0) {
        const int sel = n0 >> 10;
        if (sel < 2) {
            ushort_t* dst = (sel == 0) ? Qo : Ko;
            const float sc = (sel == 0) ? CSC : 1.0f;
            #pragma unroll
            for (int m = 0; m < 4; ++m) {
                #pragma unroll
                for (int r = 0; r < 4; ++r) {
                    int mg = m0 + wr * 64 + m * 16 + lk * 4 + r;
                    int b_ = mg >> 11, s = mg & 2047;
                    #pragma unroll
                    for (int n = 0; n < 4; ++n) {
                        int ng = n0 + wc * 64 + n * 16 + lq;
                        int h = (ng >> 6) & 15, dk = ng & 63;
                        float v = acc[m][n][r] * sc;
                        // RoPE: partner value lives in lane lq^1 (col dk^1)
                        float2 cs = *(const float2*)(tbl + ((size_t)s * 32 + (dk >> 1)) * 2);
                        float sp = __shfl_xor(v, 1);
                        float rv = (dk & 1) ? (v * cs.x + sp * cs.y)
                                            : (v * cs.x - sp * cs.y);
                        dst[(((size_t)b_ * 16 + h) * 2048 + s) * 64 + dk] = f2bf(rv);
                    }
                }
            }
        } else {
            #pragma unroll
            for (int m = 0; m < 4; ++m) {
                #pragma unroll
                for (int r = 0; r < 4; ++r) {
                    int mg = m0 + wr * 64 + m * 16 + lk * 4 + r;
                    int b_ = mg >> 11, s = mg & 2047;
                    #pragma unroll
                    for (int n = 0; n < 4; ++n) {
                        int ng = n0 + wc * 64 + n * 16 + lq;
                        int h = (ng >> 6) & 15, dk = ng & 63;
                        Vto[(((size_t)b_ * 16 + h) * 64 + dk) * 2048 + s] = f2bf(acc[m][n][r]);
                    }
                }
            }
        }
    } else {
        #pragma unroll
        for (int m = 0; m < 4; ++m) {
            #pragma unroll
            for (int r = 0; r < 4; ++r) {
                int mg = m0 + wr * 64 + m * 16 + lk * 4 + r;
                #pragma unroll
                for (int n = 0; n < 4; ++n) {
                    int ng = n0 + wc * 64 + n * 16 + lq;
                    Co[(size_t)mg * D_ + ng] = acc[m][n][r];
                }
            }
        }
    }
}

// ---------------------------------------------------------------------------
// MFMA causal flash attention, swapped-QK^T 32x32x16, kv-SPLIT across waves.
// grid 1024 (zigzag), 256 threads = 4 waves: wave w -> (wq = w&1 q-half,
// st = w>>1 kv-half). Each wave: 32 q-rows x 32-kv half-tile per iteration
// (half the serial chain of R6, 2x the waves -> 4 waves/SIMD).
// Each lane owns ONE q row; softmax in-lane + one shfl_xor(32).
// P -> PV A-operand in-register via cvt_pk + permlane32_swap.
// Epilogue: st-halves merge (m,l,O) through the dead K/V LDS buffers.
// ---------------------------------------------------------------------------
__global__ __launch_bounds__(256)
void attn_kernel(const ushort_t* __restrict__ Q, const ushort_t* __restrict__ Kg,
                 const ushort_t* __restrict__ Vt, ushort_t* __restrict__ O)
{
    __shared__ ushort_t Ks[2][64 * 64];
    __shared__ ushort_t Vs[2][64 * 64];

    const int bid = blockIdx.x;
    const int g = bid >> 8, ii = bid & 255;
    const int r8 = ii >> 3;
    const int qt = (g & 1) ? r8 : 31 - r8;
    const int bh = (ii & 7) | (g << 3);

    const int tid = threadIdx.x;                 // 0..255
    const int w = tid >> 6, lane = tid & 63;
    const int wq = w & 1, st = w >> 1;
    const int lq = lane & 31, hi = lane >> 5;
    const size_t bhBase = (size_t)bh * S_ * 64;

    // Q fragments (B-operand): lane holds Q[q][c*16 + hi*8 .. +8], q = own row
    bf16x8 qf[4];
    {
        const ushort_t* qp = Q + bhBase + (size_t)(qt * 64 + wq * 32 + lq) * 64 + hi * 8;
        qf[0] = *(const bf16x8*)(qp);
        qf[1] = *(const bf16x8*)(qp + 16);
        qf[2] = *(const bf16x8*)(qp + 32);
        qf[3] = *(const bf16x8*)(qp + 48);
    }

    // stage tile t: 512 x 16B slots per tensor; 2 iters x 256 threads.
    // Linear LDS dest, pre-swizzled global source (slot ^ (row&7), rule 21c).
    auto stage = [&](int buf, int t) {
        #pragma unroll
        for (int i = 0; i < 2; ++i) {
            int slot = i * 256 + tid;
            int rr = slot >> 3, c8 = slot & 7;
            int c8s = c8 ^ (rr & 7);
            const ushort_t* gk = Kg + bhBase + (size_t)(t * 64 + rr) * 64 + c8s * 8;
            const ushort_t* gv = Vt + bhBase + (size_t)rr * 2048 + t * 64 + c8s * 8;
            int ldsb = (i * 256 + w * 64) * 16;
            __builtin_amdgcn_global_load_lds((gas_ptr)gk, (las_ptr)((char*)Ks[buf] + ldsb), 16, 0, 0);
            __builtin_amdgcn_global_load_lds((gas_ptr)gv, (las_ptr)((char*)Vs[buf] + ldsb), 16, 0, 0);
        }
    };

    float m = -1e30f, l = 0.0f;
    f32x16 oacc[2] = {};

    stage(0, 0);

    for (int t = 0; t <= qt; ++t) {
        const int cur = t & 1;
        if (t < qt) {
            stage(cur ^ 1, t + 1);
            asm volatile("s_waitcnt vmcnt(4)" ::: "memory");   // drain current tile's 4
        } else {
            asm volatile("s_waitcnt vmcnt(0)" ::: "memory");
        }
        __builtin_amdgcn_s_barrier();
        asm volatile("" ::: "memory");

        // (wq=0, st=1) on the diagonal tile is fully masked -> skip compute
        if (!(t == qt && st > wq)) {
            // S^T[kv=32][q=32] = K-frag * Q-frag over k=64, kv half = st
            f32x16 sacc = {};
            const int row = st * 32 + lq;                // kv row in tile
            #pragma unroll
            for (int c = 0; c < 4; ++c) {
                int koff = row * 128 + ((c * 32 + hi * 16) ^ ((row & 7) << 4));
                bf16x8 kf = *(const bf16x8*)((const char*)Ks[cur] + koff);
                sacc = __builtin_amdgcn_mfma_f32_32x32x16_bf16(kf, qf[c], sacc, 0, 0, 0);
            }

            if (t == qt && st == wq) {                   // triangular 32x32 sub-tile
                #pragma unroll
                for (int idx = 0; idx < 16; ++idx) {
                    int kvl = (idx & 3) + 8 * (idx >> 2) + 4 * hi;
                    if (kvl > lq) sacc[idx] = -1e30f;
                }
            }

            float pm = sacc[0];
            #pragma unroll
            for (int idx = 1; idx < 16; ++idx) pm = fmaxf(pm, sacc[idx]);
            pm = fmaxf(pm, __shfl_xor(pm, 32));

            if (__any(pm > m + 11.5f)) {                 // defer-max (log2 domain)
                float mn = fmaxf(m, pm);
                float al = exp2f(m - mn);
                m = mn;
                l *= al;
                #pragma unroll
                for (int idx = 0; idx < 16; ++idx) { oacc[0][idx] *= al; oacc[1][idx] *= al; }
            }

            float p[16];
            #pragma unroll
            for (int idx = 0; idx < 16; ++idx) {
                float v = exp2f(sacc[idx] - m);
                p[idx] = v;
                l += v;
            }

            // PV: O^T[dk][q] += V^T-frag * P^T-frag; kv chunks of 16 within half
            #pragma unroll
            for (int c2 = 0; c2 < 2; ++c2) {
                uint_t w0 = cvtpk(p[8 * c2 + 0], p[8 * c2 + 1]);
                uint_t w1 = cvtpk(p[8 * c2 + 2], p[8 * c2 + 3]);
                uint_t w2 = cvtpk(p[8 * c2 + 4], p[8 * c2 + 5]);
                uint_t w3 = cvtpk(p[8 * c2 + 6], p[8 * c2 + 7]);
                plswap(w0, w2);
                plswap(w1, w3);
                uint32x4 pw; pw[0] = w0; pw[1] = w1; pw[2] = w2; pw[3] = w3;
                bf16x8 pb = __builtin_bit_cast(bf16x8, pw);
                #pragma unroll
                for (int d2 = 0; d2 < 2; ++d2) {
                    int vrow = d2 * 32 + lq;             // dk row
                    int voff = vrow * 128 + ((st * 64 + c2 * 32 + hi * 16) ^ ((vrow & 7) << 4));
                    bf16x8 vf = *(const bf16x8*)((const char*)Vs[cur] + voff);
                    oacc[d2] = __builtin_amdgcn_mfma_f32_32x32x16_bf16(vf, pb, oacc[d2], 0, 0, 0);
                }
            }
        }
        asm volatile("" ::: "memory");
        __builtin_amdgcn_s_barrier();                    // all reads of buf[cur] done
        asm volatile("" ::: "memory");
    }

    // combine own-row l across lane halves (kv sub-chunks)
    l += __shfl_xor(l, 32);

    // merge st=0 / st=1 partials via LDS scratch (K/V buffers are dead now).
    // Row = wq*64 + lane; bank-swizzled f32x4 slots (j ^ (row&7)).
    float* scrO  = (float*)Ks;                           // 4096 f32 (16 KB)
    float* scrML = (float*)Vs;                           // 256 f32 used
    const int rowi = wq * 64 + lane;
    if (st == 1) {
        #pragma unroll
        for (int j = 0; j < 8; ++j) {
            f32x4 v4;
            v4[0] = oacc[j >> 2][(j & 3) * 4 + 0];
            v4[1] = oacc[j >> 2][(j & 3) * 4 + 1];
            v4[2] = oacc[j >> 2][(j & 3) * 4 + 2];
            v4[3] = oacc[j >> 2][(j & 3) * 4 + 3];
            *(f32x4*)(scrO + rowi * 32 + ((j ^ (rowi & 7)) * 4)) = v4;
        }
        scrML[rowi * 2]     = m;
        scrML[rowi * 2 + 1] = l;
    }
    __syncthreads();
    if (st == 0) {
        float m1 = scrML[rowi * 2], l1 = scrML[rowi * 2 + 1];
        float M  = fmaxf(m, m1);
        float a0 = exp2f(m - M), a1 = exp2f(m1 - M);
        float lt = a0 * l + a1 * l1;
        float inv = 1.0f / lt;
        const int b_ = bh >> 4, h = bh & 15;
        const int s = qt * 64 + wq * 32 + lq;
        ushort_t* ob = O + ((size_t)b_ * 2048 + s) * 1024 + h * 64;
        #pragma unroll
        for (int j = 0; j < 8; ++j) {
            f32x4 o1 = *(const f32x4*)(scrO + rowi * 32 + ((j ^ (rowi & 7)) * 4));
            int d2 = j >> 2, base = (j & 3) * 4;
            float q0 = (a0 * oacc[d2][base + 0] + a1 * o1[0]) * inv;
            float q1 = (a0 * oacc[d2][base + 1] + a1 * o1[1]) * inv;
            float q2 = (a0 * oacc[d2][base + 2] + a1 * o1[2]) * inv;
            float q3 = (a0 * oacc[d2][base + 3] + a1 * o1[3]) * inv;
            uint2 pkv;
            pkv.x = cvtpk(q0, q1);
            pkv.y = cvtpk(q2, q3);
            *(uint2*)(ob + d2 * 32 + 8 * (j & 3) + 4 * hi) = pkv;
        }
    }
}

} // anonymous namespace

extern "C" void kernel_launch(void* const* d_in, const int* in_sizes, int n_in,
                              void* d_out, int out_size, void* d_ws, size_t ws_size,
                              hipStream_t stream)
{
    const float* x  = (const float*)d_in[0];
    const float* Wq = (const float*)d_in[1];
    const float* Wk = (const float*)d_in[2];
    const float* Wv = (const float*)d_in[3];
    const float* Wo = (const float*)d_in[4];

    ushort_t* xb  = (ushort_t*)d_ws;              // [4096][1024]        4M elems
    ushort_t* Wt  = xb  + 4194304;                // [3072][1024] (B^T)  3M elems
    ushort_t* Wot = Wt  + 3145728;                // [1024][1024] (B^T)  1M elems
    ushort_t* Qb  = Wot + 1048576;                // [32][2048][64]      4M elems
    ushort_t* Kb  = Qb  + 4194304;                // [32][2048][64]      4M elems
    ushort_t* Vtb = Kb  + 4194304;                // [32][64][2048]      4M elems
    ushort_t* Ob  = Vtb + 4194304;                // [4096][1024]        4M elems
    float*    tbl = (float*)(Ob + 4194304);       // [2048][32][2] fp32  512 KB

    conv_kernel<<<2048, 256, 0, stream>>>(x, xb);
    rope_table_kernel<<<256, 256, 0, stream>>>(tbl);
    tconv_kernel<<<dim3(16, 1, 16), 256, 0, stream>>>(Wq, Wt,           1024, 64, 65536, 65536);
    tconv_kernel<<<dim3(16, 1, 16), 256, 0, stream>>>(Wk, Wt + 1048576, 1024, 64, 65536, 65536);
    tconv_kernel<<<dim3(16, 1, 16), 256, 0, stream>>>(Wv, Wt + 2097152, 1024, 64, 65536, 65536);
    tconv_kernel<<<dim3(16, 16, 1), 256, 0, stream>>>(Wo, Wot,          1024, 1024, 0, 0);

    gemm_kernel<0><<<dim3(32, 24), 256, 0, stream>>>(xb, Wt, Qb, Kb, Vtb, nullptr, tbl, 1024);

    attn_kernel<<<1024, 256, 0, stream>>>(Qb, Kb, Vtb, Ob);

    gemm_kernel<1><<<dim3(32, 8), 256, 0, stream>>>(Ob, Wot, nullptr, nullptr, nullptr,
                                                    (float*)d_out, nullptr, 1024);
}

// Round 8
// 132.917 us; speedup vs baseline: 8.0491x; 1.1451x over previous
//
#include <hip/hip_runtime.h>
#include <math.h>

typedef __attribute__((ext_vector_type(8))) short bf16x8;
typedef __attribute__((ext_vector_type(4))) float f32x4;
typedef __attribute__((ext_vector_type(16))) float f32x16;
typedef __attribute__((ext_vector_type(4))) unsigned int uint32x4;
typedef __attribute__((ext_vector_type(2))) unsigned int uint32x2;
typedef unsigned short ushort_t;
typedef unsigned int uint_t;

typedef const void __attribute__((address_space(1)))* gas_ptr;
typedef void __attribute__((address_space(3)))* las_ptr;

namespace {

constexpr int S_  = 2048;
constexpr int D_  = 1024;
constexpr float CSC = 0.18033688011f;   // 0.125 * log2(e): score scale in log2 domain

__device__ inline ushort_t f2bf(float f) {
    uint_t u = __builtin_bit_cast(uint_t, f);
    u += 0x7FFFu + ((u >> 16) & 1u);
    return (ushort_t)(u >> 16);
}
__device__ inline float bf2f(ushort_t b) {
    uint_t u = ((uint_t)b) << 16;
    return __builtin_bit_cast(float, u);
}
__device__ inline uint_t cvtpk(float lo, float hi) {
    uint_t r;
    asm("v_cvt_pk_bf16_f32 %0, %1, %2" : "=v"(r) : "v"(lo), "v"(hi));
    return r;
}
// permlane32_swap: swaps D.hi-half-lanes with S.lo-half-lanes (verified R6).
__device__ inline void plswap(uint_t& d, uint_t& s) {
    uint32x2 r = __builtin_amdgcn_permlane32_swap(d, s, false, false);
    d = r[0];
    s = r[1];
}

// ---------------------------------------------------------------------------
// convert fp32 -> bf16, 8 elems/thread
// ---------------------------------------------------------------------------
__global__ __launch_bounds__(256)
void conv_kernel(const float* __restrict__ src, ushort_t* __restrict__ dst)
{
    int i = blockIdx.x * 256 + threadIdx.x;
    float4 a = ((const float4*)src)[i * 2];
    float4 b = ((const float4*)src)[i * 2 + 1];
    uint_t u0 = (uint_t)f2bf(a.x) | ((uint_t)f2bf(a.y) << 16);
    uint_t u1 = (uint_t)f2bf(a.z) | ((uint_t)f2bf(a.w) << 16);
    uint_t u2 = (uint_t)f2bf(b.x) | ((uint_t)f2bf(b.y) << 16);
    uint_t u3 = (uint_t)f2bf(b.z) | ((uint_t)f2bf(b.w) << 16);
    ((uint4*)dst)[i] = make_uint4(u0, u1, u2, u3);
}

// ---------------------------------------------------------------------------
// transpose + convert: src fp32 [R][C] -> dst bf16 [C][R], 64x64 tiles.
// ---------------------------------------------------------------------------
__global__ __launch_bounds__(256)
void tconv_kernel(const float* __restrict__ src, ushort_t* __restrict__ dst,
                  int R, int C, long zss, long zds)
{
    __shared__ float Tl[64][65];
    src += (size_t)blockIdx.z * zss;
    dst += (size_t)blockIdx.z * zds;
    const int r0 = blockIdx.x * 64, c0 = blockIdx.y * 64;
    const int tid = threadIdx.x;
    #pragma unroll
    for (int l = 0; l < 4; ++l) {
        int i = tid + l * 256;
        int row = i >> 4, col = (i & 15) * 4;
        float4 v = *(const float4*)(src + (size_t)(r0 + row) * C + c0 + col);
        Tl[row][col] = v.x; Tl[row][col + 1] = v.y;
        Tl[row][col + 2] = v.z; Tl[row][col + 3] = v.w;
    }
    __syncthreads();
    #pragma unroll
    for (int l = 0; l < 4; ++l) {
        int i = tid + l * 256;
        int cc = i >> 4, rr = (i & 15) * 4;
        uint_t lo = (uint_t)f2bf(Tl[rr][cc])     | ((uint_t)f2bf(Tl[rr + 1][cc]) << 16);
        uint_t hi = (uint_t)f2bf(Tl[rr + 2][cc]) | ((uint_t)f2bf(Tl[rr + 3][cc]) << 16);
        *(uint2*)(dst + (size_t)(c0 + cc) * R + r0 + rr) = make_uint2(lo, hi);
    }
}

// ---------------------------------------------------------------------------
// RoPE cos/sin table: tbl[s][p] = (cos, sin) of s * theta^(-p/32), 2048 x 32
// ---------------------------------------------------------------------------
__global__ __launch_bounds__(256)
void rope_table_kernel(float* __restrict__ tbl)
{
    int i = blockIdx.x * 256 + threadIdx.x;     // 65536 entries
    int s = i >> 5, p = i & 31;
    float inv = powf(10000.0f, -(float)p * (1.0f / 32.0f));
    float sn, cs;
    sincosf((float)s * inv, &sn, &cs);
    ((float2*)tbl)[i] = make_float2(cs, sn);
}

// ---------------------------------------------------------------------------
// m97-style bf16 MFMA GEMM: C[M][N] = A[M][K] * Bt[N][K]^T
// MODE 0: QKV epilogue: Q (pre-scaled CSC) and K get RoPE applied IN-EPILOGUE
//         (pair partner via shfl_xor(1), cos/sin from table); V transposed.
// MODE 1: fp32 epilogue -> Co[M][N]
// ---------------------------------------------------------------------------
template<int MODE>
__global__ __launch_bounds__(256)
void gemm_kernel(const ushort_t* __restrict__ A, const ushort_t* __restrict__ Bt,
                 ushort_t* __restrict__ Qo, ushort_t* __restrict__ Ko,
                 ushort_t* __restrict__ Vto, float* __restrict__ Co,
                 const float* __restrict__ tbl, int K)
{
    __shared__ ushort_t As[128 * 32];
    __shared__ ushort_t Bs[128 * 32];

    const int tid  = threadIdx.x;
    const int w    = tid >> 6, lane = tid & 63;
    const int lq   = lane & 15, lk = lane >> 4;
    const int wr   = w >> 1, wc = w & 1;
    const int m0   = blockIdx.x * 128;
    const int n0   = blockIdx.y * 128;

    f32x4 acc[4][4] = {};

    for (int k0 = 0; k0 < K; k0 += 32) {
        #pragma unroll
        for (int i = 0; i < 2; ++i) {
            int c   = i * 256 + tid;
            int row = c >> 2, c4 = c & 3;
            const ushort_t* ga = A  + (size_t)(m0 + row) * K + k0 + c4 * 8;
            const ushort_t* gb = Bt + (size_t)(n0 + row) * K + k0 + c4 * 8;
            int base = (i * 256 + w * 64) * 16;
            __builtin_amdgcn_global_load_lds((gas_ptr)ga, (las_ptr)((char*)As + base), 16, 0, 0);
            __builtin_amdgcn_global_load_lds((gas_ptr)gb, (las_ptr)((char*)Bs + base), 16, 0, 0);
        }
        __syncthreads();

        bf16x8 a[4], b[4];
        #pragma unroll
        for (int m = 0; m < 4; ++m)
            a[m] = *(const bf16x8*)((const char*)As + (wr * 64 + m * 16 + lq) * 64 + lk * 16);
        #pragma unroll
        for (int n = 0; n < 4; ++n)
            b[n] = *(const bf16x8*)((const char*)Bs + (wc * 64 + n * 16 + lq) * 64 + lk * 16);
        #pragma unroll
        for (int m = 0; m < 4; ++m)
            #pragma unroll
            for (int n = 0; n < 4; ++n)
                acc[m][n] = __builtin_amdgcn_mfma_f32_16x16x32_bf16(a[m], b[n], acc[m][n], 0, 0, 0);
        __syncthreads();
    }

    if (MODE == 0) {
        const int sel = n0 >> 10;
        if (sel < 2) {
            ushort_t* dst = (sel == 0) ? Qo : Ko;
            const float sc = (sel == 0) ? CSC : 1.0f;
            #pragma unroll
            for (int m = 0; m < 4; ++m) {
                #pragma unroll
                for (int r = 0; r < 4; ++r) {
                    int mg = m0 + wr * 64 + m * 16 + lk * 4 + r;
                    int b_ = mg >> 11, s = mg & 2047;
                    #pragma unroll
                    for (int n = 0; n < 4; ++n) {
                        int ng = n0 + wc * 64 + n * 16 + lq;
                        int h = (ng >> 6) & 15, dk = ng & 63;
                        float v = acc[m][n][r] * sc;
                        // RoPE: partner value lives in lane lq^1 (col dk^1)
                        float2 cs = *(const float2*)(tbl + ((size_t)s * 32 + (dk >> 1)) * 2);
                        float sp = __shfl_xor(v, 1);
                        float rv = (dk & 1) ? (v * cs.x + sp * cs.y)
                                            : (v * cs.x - sp * cs.y);
                        dst[(((size_t)b_ * 16 + h) * 2048 + s) * 64 + dk] = f2bf(rv);
                    }
                }
            }
        } else {
            #pragma unroll
            for (int m = 0; m < 4; ++m) {
                #pragma unroll
                for (int r = 0; r < 4; ++r) {
                    int mg = m0 + wr * 64 + m * 16 + lk * 4 + r;
                    int b_ = mg >> 11, s = mg & 2047;
                    #pragma unroll
                    for (int n = 0; n < 4; ++n) {
                        int ng = n0 + wc * 64 + n * 16 + lq;
                        int h = (ng >> 6) & 15, dk = ng & 63;
                        Vto[(((size_t)b_ * 16 + h) * 64 + dk) * 2048 + s] = f2bf(acc[m][n][r]);
                    }
                }
            }
        }
    } else {
        #pragma unroll
        for (int m = 0; m < 4; ++m) {
            #pragma unroll
            for (int r = 0; r < 4; ++r) {
                int mg = m0 + wr * 64 + m * 16 + lk * 4 + r;
                #pragma unroll
                for (int n = 0; n < 4; ++n) {
                    int ng = n0 + wc * 64 + n * 16 + lq;
                    Co[(size_t)mg * D_ + ng] = acc[m][n][r];
                }
            }
        }
    }
}

// ---------------------------------------------------------------------------
// MFMA causal flash attention, swapped-QK^T 32x32x16.
// Block = 8 waves (512 thr): wq = w&1 -> q 32-half of a 64-row q-tile,
// st = w>>2? no: st = w>>1 (0..3) -> kv 32-quarter of a 128-kv tile.
// Worst-case serial depth = 16 kv-tile iterations (vs 32 at kv=64).
// Per-wave inner math identical to the R7-verified 32q x 32kv algebra.
// K [128 kv][64 dk], V^T [64 dk][128 kv] staged via global_load_lds with
// pre-swizzled source, double-buffered, counted vmcnt(4).
// Epilogue: 4-way (m,l,O) merge through the dead K/V LDS buffers.
// ---------------------------------------------------------------------------
__global__ __launch_bounds__(512)
void attn_kernel(const ushort_t* __restrict__ Q, const ushort_t* __restrict__ Kg,
                 const ushort_t* __restrict__ Vt, ushort_t* __restrict__ O)
{
    __shared__ ushort_t Ks[2][128 * 64];   // [kv][dk], row stride 128 B
    __shared__ ushort_t Vs[2][64 * 128];   // [dk][kv], row stride 256 B

    const int bid = blockIdx.x;
    const int p  = 31 - (bid >> 5);        // q-tile index, longest first
    const int bh = bid & 31;

    const int tid = threadIdx.x;           // 0..511
    const int w = tid >> 6, lane = tid & 63;
    const int wq = w & 1, st = w >> 1;     // q-half, kv-quarter
    const int lq = lane & 31, hi = lane >> 5;
    const size_t bhBase = (size_t)bh * S_ * 64;

    const int nt   = (p >> 1) + 1;         // kv 128-tiles to process
    const int qrel = ((p & 1) << 1) + wq;  // which kv-quarter is diagonal on last tile

    // Q fragments (B-operand): lane holds Q[q][c*16 + hi*8 .. +8]
    bf16x8 qf[4];
    {
        const ushort_t* qp = Q + bhBase + (size_t)(p * 64 + wq * 32 + lq) * 64 + hi * 8;
        qf[0] = *(const bf16x8*)(qp);
        qf[1] = *(const bf16x8*)(qp + 16);
        qf[2] = *(const bf16x8*)(qp + 32);
        qf[3] = *(const bf16x8*)(qp + 48);
    }

    // staging geometry: 1024 x 16B slots per tensor, 2 slots/thread each.
    // Linear LDS dest = slot*16 (wave-uniform base + lane*16); global source
    // pre-swizzled (slot ^ (row&7)) so the swizzled read sees natural layout.
    const int slot0 = tid, slot1 = 512 + tid;
    const int rK0 = slot0 >> 3, rK1 = slot1 >> 3;
    const int rV0 = slot0 >> 4, rV1 = slot1 >> 4;
    const ushort_t* gk0 = Kg + bhBase + (size_t)rK0 * 64 + ((slot0 & 7) ^ (rK0 & 7)) * 8;
    const ushort_t* gk1 = Kg + bhBase + (size_t)rK1 * 64 + ((slot1 & 7) ^ (rK1 & 7)) * 8;
    const ushort_t* gv0 = Vt + bhBase + (size_t)rV0 * 2048 + ((slot0 & 15) ^ (rV0 & 7)) * 8;
    const ushort_t* gv1 = Vt + bhBase + (size_t)rV1 * 2048 + ((slot1 & 15) ^ (rV1 & 7)) * 8;

    auto stage = [&](int buf, int t) {
        const size_t ko = (size_t)t * 128 * 64;   // K advances 128 rows/tile
        const size_t vo = (size_t)t * 128;        // V advances 128 kv cols/tile
        __builtin_amdgcn_global_load_lds((gas_ptr)(gk0 + ko), (las_ptr)((char*)Ks[buf] + slot0 * 16), 16, 0, 0);
        __builtin_amdgcn_global_load_lds((gas_ptr)(gk1 + ko), (las_ptr)((char*)Ks[buf] + slot1 * 16), 16, 0, 0);
        __builtin_amdgcn_global_load_lds((gas_ptr)(gv0 + vo), (las_ptr)((char*)Vs[buf] + slot0 * 16), 16, 0, 0);
        __builtin_amdgcn_global_load_lds((gas_ptr)(gv1 + vo), (las_ptr)((char*)Vs[buf] + slot1 * 16), 16, 0, 0);
    };

    float m = -1e30f, l = 0.0f;
    f32x16 oacc[2] = {};

    const int krow = st * 32 + lq;         // this wave's kv row in the 128-tile

    stage(0, 0);

    for (int t = 0; t < nt; ++t) {
        const int cur = t & 1;
        if (t < nt - 1) {
            stage(cur ^ 1, t + 1);
            asm volatile("s_waitcnt vmcnt(4)" ::: "memory");   // drain current tile's 4
        } else {
            asm volatile("s_waitcnt vmcnt(0)" ::: "memory");
        }
        __builtin_amdgcn_s_barrier();
        asm volatile("" ::: "memory");

        const bool last = (t == nt - 1);
        if (!(last && st > qrel)) {        // fully-masked quarter: staging only
            // S^T[kv=32][q=32] = K-frag * Q-frag over k=64
            f32x16 sacc = {};
            #pragma unroll
            for (int c = 0; c < 4; ++c) {
                int koff = krow * 128 + ((c * 32 + hi * 16) ^ ((krow & 7) << 4));
                bf16x8 kf = *(const bf16x8*)((const char*)Ks[cur] + koff);
                sacc = __builtin_amdgcn_mfma_f32_32x32x16_bf16(kf, qf[c], sacc, 0, 0, 0);
            }

            if (last && st == qrel) {      // triangular 32x32 sub-tile
                #pragma unroll
                for (int idx = 0; idx < 16; ++idx) {
                    int kvl = (idx & 3) + 8 * (idx >> 2) + 4 * hi;
                    if (kvl > lq) sacc[idx] = -1e30f;
                }
            }

            float pm = sacc[0];
            #pragma unroll
            for (int idx = 1; idx < 16; ++idx) pm = fmaxf(pm, sacc[idx]);
            pm = fmaxf(pm, __shfl_xor(pm, 32));

            if (__any(pm > m + 11.5f)) {   // defer-max (log2 domain)
                float mn = fmaxf(m, pm);
                float al = exp2f(m - mn);
                m = mn;
                l *= al;
                #pragma unroll
                for (int idx = 0; idx < 16; ++idx) { oacc[0][idx] *= al; oacc[1][idx] *= al; }
            }

            float pv[16];
            #pragma unroll
            for (int idx = 0; idx < 16; ++idx) {
                float v = exp2f(sacc[idx] - m);
                pv[idx] = v;
                l += v;
            }

            // PV: O^T[dk][q] += V^T-frag * P^T-frag; kv chunks of 16 in this quarter
            #pragma unroll
            for (int c2 = 0; c2 < 2; ++c2) {
                uint_t w0 = cvtpk(pv[8 * c2 + 0], pv[8 * c2 + 1]);
                uint_t w1 = cvtpk(pv[8 * c2 + 2], pv[8 * c2 + 3]);
                uint_t w2 = cvtpk(pv[8 * c2 + 4], pv[8 * c2 + 5]);
                uint_t w3 = cvtpk(pv[8 * c2 + 6], pv[8 * c2 + 7]);
                plswap(w0, w2);
                plswap(w1, w3);
                uint32x4 pw; pw[0] = w0; pw[1] = w1; pw[2] = w2; pw[3] = w3;
                bf16x8 pb = __builtin_bit_cast(bf16x8, pw);
                #pragma unroll
                for (int d2 = 0; d2 < 2; ++d2) {
                    int vrow = d2 * 32 + lq;   // dk row; V row stride = 16 slots
                    int vslot = (st * 4 + c2 * 2 + hi) ^ (vrow & 7);
                    bf16x8 vf = *(const bf16x8*)((const char*)Vs[cur] + vrow * 256 + vslot * 16);
                    oacc[d2] = __builtin_amdgcn_mfma_f32_32x32x16_bf16(vf, pb, oacc[d2], 0, 0, 0);
                }
            }
        }
        asm volatile("" ::: "memory");
        __builtin_amdgcn_s_barrier();      // all reads of buf[cur] done
        asm volatile("" ::: "memory");
    }

    // combine own-row l across lane halves (kv sub-chunks)
    l += __shfl_xor(l, 32);

    __syncthreads();                       // LDS now dead -> reuse as merge scratch

    // scratch: st=1 -> Ks floats [0,4096); st=2 -> Ks [4096,8192);
    //          st=3 -> Vs [0,4096); m,l -> Vs [4096 + (st-1)*256 + rowi*2]
    float* ksf = (float*)Ks;
    float* vsf = (float*)Vs;
    const int rowi = wq * 64 + lane;       // 0..127 (lane halves hold distinct dk slices)
    if (st != 0) {
        float* dst = (st == 1) ? ksf : (st == 2) ? (ksf + 4096) : vsf;
        #pragma unroll
        for (int j = 0; j < 8; ++j) {
            f32x4 v4;
            v4[0] = oacc[j >> 2][(j & 3) * 4 + 0];
            v4[1] = oacc[j >> 2][(j & 3) * 4 + 1];
            v4[2] = oacc[j >> 2][(j & 3) * 4 + 2];
            v4[3] = oacc[j >> 2][(j & 3) * 4 + 3];
            *(f32x4*)(dst + rowi * 32 + ((j ^ (rowi & 7)) * 4)) = v4;
        }
        vsf[4096 + (st - 1) * 512 + rowi * 2]     = m;
        vsf[4096 + (st - 1) * 512 + rowi * 2 + 1] = l;
    }
    __syncthreads();
    if (st == 0) {
        float ms[3], ls[3];
        #pragma unroll
        for (int s2 = 0; s2 < 3; ++s2) {
            ms[s2] = vsf[4096 + s2 * 512 + rowi * 2];
            ls[s2] = vsf[4096 + s2 * 512 + rowi * 2 + 1];
        }
        float M = fmaxf(fmaxf(m, ms[0]), fmaxf(ms[1], ms[2]));
        float a0 = exp2f(m - M);
        float a1 = exp2f(ms[0] - M), a2 = exp2f(ms[1] - M), a3 = exp2f(ms[2] - M);
        float lt = a0 * l + a1 * ls[0] + a2 * ls[1] + a3 * ls[2];
        float inv = 1.0f / lt;
        const int b_ = bh >> 4, h = bh & 15;
        const int s = p * 64 + wq * 32 + lq;
        ushort_t* ob = O + ((size_t)b_ * 2048 + s) * 1024 + h * 64;
        #pragma unroll
        for (int j = 0; j < 8; ++j) {
            int soff = rowi * 32 + ((j ^ (rowi & 7)) * 4);
            f32x4 o1 = *(const f32x4*)(ksf + soff);
            f32x4 o2 = *(const f32x4*)(ksf + 4096 + soff);
            f32x4 o3 = *(const f32x4*)(vsf + soff);
            int d2 = j >> 2, base = (j & 3) * 4;
            float q0 = (a0 * oacc[d2][base + 0] + a1 * o1[0] + a2 * o2[0] + a3 * o3[0]) * inv;
            float q1 = (a0 * oacc[d2][base + 1] + a1 * o1[1] + a2 * o2[1] + a3 * o3[1]) * inv;
            float q2 = (a0 * oacc[d2][base + 2] + a1 * o1[2] + a2 * o2[2] + a3 * o3[2]) * inv;
            float q3 = (a0 * oacc[d2][base + 3] + a1 * o1[3] + a2 * o2[3] + a3 * o3[3]) * inv;
            uint2 pkv;
            pkv.x = cvtpk(q0, q1);
            pkv.y = cvtpk(q2, q3);
            *(uint2*)(ob + d2 * 32 + 8 * (j & 3) + 4 * hi) = pkv;
        }
    }
}

} // anonymous namespace

extern "C" void kernel_launch(void* const* d_in, const int* in_sizes, int n_in,
                              void* d_out, int out_size, void* d_ws, size_t ws_size,
                              hipStream_t stream)
{
    const float* x  = (const float*)d_in[0];
    const float* Wq = (const float*)d_in[1];
    const float* Wk = (const float*)d_in[2];
    const float* Wv = (const float*)d_in[3];
    const float* Wo = (const float*)d_in[4];

    ushort_t* xb  = (ushort_t*)d_ws;              // [4096][1024]        4M elems
    ushort_t* Wt  = xb  + 4194304;                // [3072][1024] (B^T)  3M elems
    ushort_t* Wot = Wt  + 3145728;                // [1024][1024] (B^T)  1M elems
    ushort_t* Qb  = Wot + 1048576;                // [32][2048][64]      4M elems
    ushort_t* Kb  = Qb  + 4194304;                // [32][2048][64]      4M elems
    ushort_t* Vtb = Kb  + 4194304;                // [32][64][2048]      4M elems
    ushort_t* Ob  = Vtb + 4194304;                // [4096][1024]        4M elems
    float*    tbl = (float*)(Ob + 4194304);       // [2048][32][2] fp32  512 KB

    conv_kernel<<<2048, 256, 0, stream>>>(x, xb);
    rope_table_kernel<<<256, 256, 0, stream>>>(tbl);
    tconv_kernel<<<dim3(16, 1, 16), 256, 0, stream>>>(Wq, Wt,           1024, 64, 65536, 65536);
    tconv_kernel<<<dim3(16, 1, 16), 256, 0, stream>>>(Wk, Wt + 1048576, 1024, 64, 65536, 65536);
    tconv_kernel<<<dim3(16, 1, 16), 256, 0, stream>>>(Wv, Wt + 2097152, 1024, 64, 65536, 65536);
    tconv_kernel<<<dim3(16, 16, 1), 256, 0, stream>>>(Wo, Wot,          1024, 1024, 0, 0);

    gemm_kernel<0><<<dim3(32, 24), 256, 0, stream>>>(xb, Wt, Qb, Kb, Vtb, nullptr, tbl, 1024);

    attn_kernel<<<1024, 512, 0, stream>>>(Qb, Kb, Vtb, Ob);

    gemm_kernel<1><<<dim3(32, 8), 256, 0, stream>>>(Ob, Wot, nullptr, nullptr, nullptr,
                                                    (float*)d_out, nullptr, 1024);
}

// Round 9
// 129.279 us; speedup vs baseline: 8.2757x; 1.0281x over previous
//
#include <hip/hip_runtime.h>
#include <math.h>

typedef __attribute__((ext_vector_type(8))) short bf16x8;
typedef __attribute__((ext_vector_type(4))) float f32x4;
typedef __attribute__((ext_vector_type(16))) float f32x16;
typedef __attribute__((ext_vector_type(4))) unsigned int uint32x4;
typedef __attribute__((ext_vector_type(2))) unsigned int uint32x2;
typedef unsigned short ushort_t;
typedef unsigned int uint_t;

typedef const void __attribute__((address_space(1)))* gas_ptr;
typedef void __attribute__((address_space(3)))* las_ptr;

namespace {

constexpr int S_  = 2048;
constexpr int D_  = 1024;
constexpr float CSC = 0.18033688011f;   // 0.125 * log2(e): score scale in log2 domain

__device__ inline ushort_t f2bf(float f) {
    uint_t u = __builtin_bit_cast(uint_t, f);
    u += 0x7FFFu + ((u >> 16) & 1u);
    return (ushort_t)(u >> 16);
}
__device__ inline uint_t cvtpk(float lo, float hi) {
    uint_t r;
    asm("v_cvt_pk_bf16_f32 %0, %1, %2" : "=v"(r) : "v"(lo), "v"(hi));
    return r;
}
// permlane32_swap: swaps D.hi-half-lanes with S.lo-half-lanes (verified R6).
__device__ inline void plswap(uint_t& d, uint_t& s) {
    uint32x2 r = __builtin_amdgcn_permlane32_swap(d, s, false, false);
    d = r[0];
    s = r[1];
}

// ---------------------------------------------------------------------------
// convert fp32 -> bf16, 8 elems/thread
// ---------------------------------------------------------------------------
__global__ __launch_bounds__(256)
void conv_kernel(const float* __restrict__ src, ushort_t* __restrict__ dst)
{
    int i = blockIdx.x * 256 + threadIdx.x;
    float4 a = ((const float4*)src)[i * 2];
    float4 b = ((const float4*)src)[i * 2 + 1];
    uint_t u0 = (uint_t)f2bf(a.x) | ((uint_t)f2bf(a.y) << 16);
    uint_t u1 = (uint_t)f2bf(a.z) | ((uint_t)f2bf(a.w) << 16);
    uint_t u2 = (uint_t)f2bf(b.x) | ((uint_t)f2bf(b.y) << 16);
    uint_t u3 = (uint_t)f2bf(b.z) | ((uint_t)f2bf(b.w) << 16);
    ((uint4*)dst)[i] = make_uint4(u0, u1, u2, u3);
}

// ---------------------------------------------------------------------------
// transpose + convert fp32 [R][C] -> bf16 [C][R] in 64x64 tiles.
// tconv3: all three QKV weights in one launch (z = 0..47).
// ---------------------------------------------------------------------------
__device__ inline void tconv_body(const float* __restrict__ src,
                                  ushort_t* __restrict__ dst,
                                  int R, int C, int r0, int c0, int tid)
{
    __shared__ float Tl[64][65];
    #pragma unroll
    for (int l = 0; l < 4; ++l) {
        int i = tid + l * 256;
        int row = i >> 4, col = (i & 15) * 4;
        float4 v = *(const float4*)(src + (size_t)(r0 + row) * C + c0 + col);
        Tl[row][col] = v.x; Tl[row][col + 1] = v.y;
        Tl[row][col + 2] = v.z; Tl[row][col + 3] = v.w;
    }
    __syncthreads();
    #pragma unroll
    for (int l = 0; l < 4; ++l) {
        int i = tid + l * 256;
        int cc = i >> 4, rr = (i & 15) * 4;
        uint_t lo = (uint_t)f2bf(Tl[rr][cc])     | ((uint_t)f2bf(Tl[rr + 1][cc]) << 16);
        uint_t hi = (uint_t)f2bf(Tl[rr + 2][cc]) | ((uint_t)f2bf(Tl[rr + 3][cc]) << 16);
        *(uint2*)(dst + (size_t)(c0 + cc) * R + r0 + rr) = make_uint2(lo, hi);
    }
}

__global__ __launch_bounds__(256)
void tconv3_kernel(const float* __restrict__ Wq, const float* __restrict__ Wk,
                   const float* __restrict__ Wv, ushort_t* __restrict__ dst)
{
    const int z = blockIdx.z;                    // 0..47
    const float* src = (z < 16 ? Wq : z < 32 ? Wk : Wv) + (size_t)(z & 15) * 65536;
    tconv_body(src, dst + (size_t)z * 65536, 1024, 64, blockIdx.x * 64, 0, threadIdx.x);
}

__global__ __launch_bounds__(256)
void tconv_kernel(const float* __restrict__ src, ushort_t* __restrict__ dst, int R, int C)
{
    tconv_body(src, dst, R, C, blockIdx.x * 64, blockIdx.y * 64, threadIdx.x);
}

// ---------------------------------------------------------------------------
// RoPE cos/sin table: tbl[s][p] = (cos, sin) of s * theta^(-p/32), 2048 x 32
// ---------------------------------------------------------------------------
__global__ __launch_bounds__(256)
void rope_table_kernel(float* __restrict__ tbl)
{
    int i = blockIdx.x * 256 + threadIdx.x;     // 65536 entries
    int s = i >> 5, p = i & 31;
    float inv = powf(10000.0f, -(float)p * (1.0f / 32.0f));
    float sn, cs;
    sincosf((float)s * inv, &sn, &cs);
    ((float2*)tbl)[i] = make_float2(cs, sn);
}

// ---------------------------------------------------------------------------
// m97-style bf16 MFMA GEMM: C[M][N] = A[M][K] * Bt[N][K]^T
// MODE 0: QKV epilogue via LDS-transpose for coalesced 16B stores:
//         Q (pre-scaled CSC) and K RoPE'd in-epilogue; V stored transposed.
// MODE 1: fp32 epilogue -> Co[M][N]
// ---------------------------------------------------------------------------
template<int MODE>
__global__ __launch_bounds__(256)
void gemm_kernel(const ushort_t* __restrict__ A, const ushort_t* __restrict__ Bt,
                 ushort_t* __restrict__ Qo, ushort_t* __restrict__ Ko,
                 ushort_t* __restrict__ Vto, float* __restrict__ Co,
                 const float* __restrict__ tbl, int K)
{
    constexpr int SMEM_BYTES = (MODE == 0) ? 34816 : 16384;  // EP 128x136 u16 : staging
    __shared__ char smem[SMEM_BYTES];
    ushort_t* As = (ushort_t*)smem;          // 128x32 (8 KB)
    ushort_t* Bs = As + 4096;                // 128x32 (8 KB)

    const int tid  = threadIdx.x;
    const int w    = tid >> 6, lane = tid & 63;
    const int lq   = lane & 15, lk = lane >> 4;
    const int wr   = w >> 1, wc = w & 1;
    const int m0   = blockIdx.x * 128;
    const int n0   = blockIdx.y * 128;

    f32x4 acc[4][4] = {};

    for (int k0 = 0; k0 < K; k0 += 32) {
        #pragma unroll
        for (int i = 0; i < 2; ++i) {
            int c   = i * 256 + tid;
            int row = c >> 2, c4 = c & 3;
            const ushort_t* ga = A  + (size_t)(m0 + row) * K + k0 + c4 * 8;
            const ushort_t* gb = Bt + (size_t)(n0 + row) * K + k0 + c4 * 8;
            int base = (i * 256 + w * 64) * 16;
            __builtin_amdgcn_global_load_lds((gas_ptr)ga, (las_ptr)((char*)As + base), 16, 0, 0);
            __builtin_amdgcn_global_load_lds((gas_ptr)gb, (las_ptr)((char*)Bs + base), 16, 0, 0);
        }
        __syncthreads();

        bf16x8 a[4], b[4];
        #pragma unroll
        for (int m = 0; m < 4; ++m)
            a[m] = *(const bf16x8*)((const char*)As + (wr * 64 + m * 16 + lq) * 64 + lk * 16);
        #pragma unroll
        for (int n = 0; n < 4; ++n)
            b[n] = *(const bf16x8*)((const char*)Bs + (wc * 64 + n * 16 + lq) * 64 + lk * 16);
        #pragma unroll
        for (int m = 0; m < 4; ++m)
            #pragma unroll
            for (int n = 0; n < 4; ++n)
                acc[m][n] = __builtin_amdgcn_mfma_f32_16x16x32_bf16(a[m], b[n], acc[m][n], 0, 0, 0);
        __syncthreads();
    }

    if (MODE == 0) {
        const int sel = n0 >> 10;
        ushort_t* EP = (ushort_t*)smem;          // 128 rows x 136 (pad) u16
        const int h0 = (n0 & 1023) >> 6;         // head base for this 128-col tile
        if (sel < 2) {
            const float sc = (sel == 0) ? CSC : 1.0f;
            #pragma unroll
            for (int m = 0; m < 4; ++m) {
                #pragma unroll
                for (int r = 0; r < 4; ++r) {
                    int lrow = wr * 64 + m * 16 + lk * 4 + r;
                    int sG = (m0 + lrow) & 2047;
                    #pragma unroll
                    for (int n = 0; n < 4; ++n) {
                        int lcol = wc * 64 + n * 16 + lq;
                        int dk = lcol & 63;
                        float v = acc[m][n][r] * sc;
                        float2 cs = *(const float2*)(tbl + ((size_t)sG * 32 + (dk >> 1)) * 2);
                        float sp = __shfl_xor(v, 1);       // partner col dk^1
                        float rv = (dk & 1) ? (v * cs.x + sp * cs.y)
                                            : (v * cs.x - sp * cs.y);
                        EP[lrow * 136 + lcol] = f2bf(rv);
                    }
                }
            }
            __syncthreads();
            ushort_t* dst = (sel == 0) ? Qo : Ko;
            #pragma unroll
            for (int it = 0; it < 8; ++it) {
                int idx = it * 256 + tid;
                int row = idx >> 4, c16 = idx & 15;
                uint4 v = *(const uint4*)(EP + row * 136 + c16 * 8);
                int mg = m0 + row;
                int b_ = mg >> 11, s = mg & 2047;
                int h = h0 + (c16 >> 3);
                int dk0 = (c16 & 7) * 8;
                *(uint4*)(dst + (((size_t)b_ * 16 + h) * 2048 + s) * 64 + dk0) = v;
            }
        } else {
            // V: write col-major into EP -> transpose is free; coalesced stores
            #pragma unroll
            for (int m = 0; m < 4; ++m) {
                #pragma unroll
                for (int r = 0; r < 4; ++r) {
                    int lrow = wr * 64 + m * 16 + lk * 4 + r;
                    #pragma unroll
                    for (int n = 0; n < 4; ++n) {
                        int lcol = wc * 64 + n * 16 + lq;
                        EP[lcol * 136 + lrow] = f2bf(acc[m][n][r]);
                    }
                }
            }
            __syncthreads();
            #pragma unroll
            for (int it = 0; it < 8; ++it) {
                int idx = it * 256 + tid;
                int col = idx >> 4, c16 = idx & 15;
                uint4 v = *(const uint4*)(EP + col * 136 + c16 * 8);
                int h = h0 + (col >> 6);
                int dk = col & 63;
                int sb = m0 + c16 * 8;
                int b_ = sb >> 11, s = sb & 2047;
                *(uint4*)(Vto + (((size_t)b_ * 16 + h) * 64 + dk) * 2048 + s) = v;
            }
        }
    } else {
        #pragma unroll
        for (int m = 0; m < 4; ++m) {
            #pragma unroll
            for (int r = 0; r < 4; ++r) {
                int mg = m0 + wr * 64 + m * 16 + lk * 4 + r;
                #pragma unroll
                for (int n = 0; n < 4; ++n) {
                    int ng = n0 + wc * 64 + n * 16 + lq;
                    Co[(size_t)mg * D_ + ng] = acc[m][n][r];
                }
            }
        }
    }
}

// ---------------------------------------------------------------------------
// MFMA causal flash attention, swapped-QK^T 32x32x16 (R8-verified algebra).
// Block = 8 waves: wq = w&1 (q 32-half of 64-row q-tile), st = w>>1 (kv
// 32-quarter of 128-kv tile). bid mapped so bid%8 = bh%8 (XCD L2 locality)
// and longest q-tiles dispatch first. setprio(1) around MFMA clusters.
// ---------------------------------------------------------------------------
__global__ __launch_bounds__(512)
void attn_kernel(const ushort_t* __restrict__ Q, const ushort_t* __restrict__ Kg,
                 const ushort_t* __restrict__ Vt, ushort_t* __restrict__ O)
{
    __shared__ ushort_t Ks[2][128 * 64];   // [kv][dk], row stride 128 B
    __shared__ ushort_t Vs[2][64 * 128];   // [dk][kv], row stride 256 B

    // decode: bhlow = bid&7 pins bh%8 to an XCD; r>>2 walks q-tiles longest-first
    const int bid = blockIdx.x;
    const int bhlow = bid & 7;
    const int r  = bid >> 3;               // 0..127
    const int p  = 31 - (r >> 2);          // q-tile index, longest first
    const int bh = ((r & 3) << 3) | bhlow;

    const int tid = threadIdx.x;           // 0..511
    const int w = tid >> 6, lane = tid & 63;
    const int wq = w & 1, st = w >> 1;     // q-half, kv-quarter
    const int lq = lane & 31, hi = lane >> 5;
    const size_t bhBase = (size_t)bh * S_ * 64;

    const int nt   = (p >> 1) + 1;         // kv 128-tiles to process
    const int qrel = ((p & 1) << 1) + wq;  // diagonal kv-quarter on last tile

    // Q fragments (B-operand): lane holds Q[q][c*16 + hi*8 .. +8]
    bf16x8 qf[4];
    {
        const ushort_t* qp = Q + bhBase + (size_t)(p * 64 + wq * 32 + lq) * 64 + hi * 8;
        qf[0] = *(const bf16x8*)(qp);
        qf[1] = *(const bf16x8*)(qp + 16);
        qf[2] = *(const bf16x8*)(qp + 32);
        qf[3] = *(const bf16x8*)(qp + 48);
    }

    // staging: 1024 x 16B slots per tensor, 2 slots/thread each; linear LDS
    // dest, pre-swizzled global source (slot ^ (row&7), rule 21c).
    const int slot0 = tid, slot1 = 512 + tid;
    const int rK0 = slot0 >> 3, rK1 = slot1 >> 3;
    const int rV0 = slot0 >> 4, rV1 = slot1 >> 4;
    const ushort_t* gk0 = Kg + bhBase + (size_t)rK0 * 64 + ((slot0 & 7) ^ (rK0 & 7)) * 8;
    const ushort_t* gk1 = Kg + bhBase + (size_t)rK1 * 64 + ((slot1 & 7) ^ (rK1 & 7)) * 8;
    const ushort_t* gv0 = Vt + bhBase + (size_t)rV0 * 2048 + ((slot0 & 15) ^ (rV0 & 7)) * 8;
    const ushort_t* gv1 = Vt + bhBase + (size_t)rV1 * 2048 + ((slot1 & 15) ^ (rV1 & 7)) * 8;

    auto stage = [&](int buf, int t) {
        const size_t ko = (size_t)t * 128 * 64;   // K advances 128 rows/tile
        const size_t vo = (size_t)t * 128;        // V advances 128 kv cols/tile
        __builtin_amdgcn_global_load_lds((gas_ptr)(gk0 + ko), (las_ptr)((char*)Ks[buf] + slot0 * 16), 16, 0, 0);
        __builtin_amdgcn_global_load_lds((gas_ptr)(gk1 + ko), (las_ptr)((char*)Ks[buf] + slot1 * 16), 16, 0, 0);
        __builtin_amdgcn_global_load_lds((gas_ptr)(gv0 + vo), (las_ptr)((char*)Vs[buf] + slot0 * 16), 16, 0, 0);
        __builtin_amdgcn_global_load_lds((gas_ptr)(gv1 + vo), (las_ptr)((char*)Vs[buf] + slot1 * 16), 16, 0, 0);
    };

    float m = -1e30f, l = 0.0f;
    f32x16 oacc[2] = {};

    const int krow = st * 32 + lq;         // this wave's kv row in the 128-tile

    stage(0, 0);

    for (int t = 0; t < nt; ++t) {
        const int cur = t & 1;
        if (t < nt - 1) {
            stage(cur ^ 1, t + 1);
            asm volatile("s_waitcnt vmcnt(4)" ::: "memory");   // drain current tile's 4
        } else {
            asm volatile("s_waitcnt vmcnt(0)" ::: "memory");
        }
        __builtin_amdgcn_s_barrier();
        asm volatile("" ::: "memory");

        const bool last = (t == nt - 1);
        if (!(last && st > qrel)) {        // fully-masked quarter: staging only
            // S^T[kv=32][q=32] = K-frag * Q-frag over k=64
            f32x16 sacc = {};
            __builtin_amdgcn_s_setprio(1);
            #pragma unroll
            for (int c = 0; c < 4; ++c) {
                int koff = krow * 128 + ((c * 32 + hi * 16) ^ ((krow & 7) << 4));
                bf16x8 kf = *(const bf16x8*)((const char*)Ks[cur] + koff);
                sacc = __builtin_amdgcn_mfma_f32_32x32x16_bf16(kf, qf[c], sacc, 0, 0, 0);
            }
            __builtin_amdgcn_s_setprio(0);

            if (last && st == qrel) {      // triangular 32x32 sub-tile
                #pragma unroll
                for (int idx = 0; idx < 16; ++idx) {
                    int kvl = (idx & 3) + 8 * (idx >> 2) + 4 * hi;
                    if (kvl > lq) sacc[idx] = -1e30f;
                }
            }

            float pm = fmaxf(sacc[0], sacc[1]);
            #pragma unroll
            for (int idx = 2; idx < 16; idx += 2)
                pm = fmaxf(fmaxf(pm, sacc[idx]), sacc[idx + 1]);   // v_max3 pairs
            pm = fmaxf(pm, __shfl_xor(pm, 32));

            if (__any(pm > m + 11.5f)) {   // defer-max (log2 domain)
                float mn = fmaxf(m, pm);
                float al = exp2f(m - mn);
                m = mn;
                l *= al;
                #pragma unroll
                for (int idx = 0; idx < 16; ++idx) { oacc[0][idx] *= al; oacc[1][idx] *= al; }
            }

            float pv[16];
            #pragma unroll
            for (int idx = 0; idx < 16; ++idx) {
                float v = exp2f(sacc[idx] - m);
                pv[idx] = v;
                l += v;
            }

            // PV: O^T[dk][q] += V^T-frag * P^T-frag; kv chunks of 16 in this quarter
            #pragma unroll
            for (int c2 = 0; c2 < 2; ++c2) {
                uint_t w0 = cvtpk(pv[8 * c2 + 0], pv[8 * c2 + 1]);
                uint_t w1 = cvtpk(pv[8 * c2 + 2], pv[8 * c2 + 3]);
                uint_t w2 = cvtpk(pv[8 * c2 + 4], pv[8 * c2 + 5]);
                uint_t w3 = cvtpk(pv[8 * c2 + 6], pv[8 * c2 + 7]);
                plswap(w0, w2);
                plswap(w1, w3);
                uint32x4 pw; pw[0] = w0; pw[1] = w1; pw[2] = w2; pw[3] = w3;
                bf16x8 pb = __builtin_bit_cast(bf16x8, pw);
                __builtin_amdgcn_s_setprio(1);
                #pragma unroll
                for (int d2 = 0; d2 < 2; ++d2) {
                    int vrow = d2 * 32 + lq;   // dk row; V row stride = 16 slots
                    int vslot = (st * 4 + c2 * 2 + hi) ^ (vrow & 7);
                    bf16x8 vf = *(const bf16x8*)((const char*)Vs[cur] + vrow * 256 + vslot * 16);
                    oacc[d2] = __builtin_amdgcn_mfma_f32_32x32x16_bf16(vf, pb, oacc[d2], 0, 0, 0);
                }
                __builtin_amdgcn_s_setprio(0);
            }
        }
        asm volatile("" ::: "memory");
        __builtin_amdgcn_s_barrier();      // all reads of buf[cur] done
        asm volatile("" ::: "memory");
    }

    // combine own-row l across lane halves (kv sub-chunks)
    l += __shfl_xor(l, 32);

    __syncthreads();                       // LDS now dead -> reuse as merge scratch

    // scratch: st=1 -> Ks floats [0,4096); st=2 -> Ks [4096,8192);
    //          st=3 -> Vs [0,4096); m,l -> Vs [4096 + (st-1)*512 + rowi*2]
    float* ksf = (float*)Ks;
    float* vsf = (float*)Vs;
    const int rowi = wq * 64 + lane;       // 0..127
    if (st != 0) {
        float* dst = (st == 1) ? ksf : (st == 2) ? (ksf + 4096) : vsf;
        #pragma unroll
        for (int j = 0; j < 8; ++j) {
            f32x4 v4;
            v4[0] = oacc[j >> 2][(j & 3) * 4 + 0];
            v4[1] = oacc[j >> 2][(j & 3) * 4 + 1];
            v4[2] = oacc[j >> 2][(j & 3) * 4 + 2];
            v4[3] = oacc[j >> 2][(j & 3) * 4 + 3];
            *(f32x4*)(dst + rowi * 32 + ((j ^ (rowi & 7)) * 4)) = v4;
        }
        vsf[4096 + (st - 1) * 512 + rowi * 2]     = m;
        vsf[4096 + (st - 1) * 512 + rowi * 2 + 1] = l;
    }
    __syncthreads();
    if (st == 0) {
        float ms[3], ls[3];
        #pragma unroll
        for (int s2 = 0; s2 < 3; ++s2) {
            ms[s2] = vsf[4096 + s2 * 512 + rowi * 2];
            ls[s2] = vsf[4096 + s2 * 512 + rowi * 2 + 1];
        }
        float M = fmaxf(fmaxf(m, ms[0]), fmaxf(ms[1], ms[2]));
        float a0 = exp2f(m - M);
        float a1 = exp2f(ms[0] - M), a2 = exp2f(ms[1] - M), a3 = exp2f(ms[2] - M);
        float lt = a0 * l + a1 * ls[0] + a2 * ls[1] + a3 * ls[2];
        float inv = 1.0f / lt;
        const int b_ = bh >> 4, h = bh & 15;
        const int s = p * 64 + wq * 32 + lq;
        ushort_t* ob = O + ((size_t)b_ * 2048 + s) * 1024 + h * 64;
        #pragma unroll
        for (int j = 0; j < 8; ++j) {
            int soff = rowi * 32 + ((j ^ (rowi & 7)) * 4);
            f32x4 o1 = *(const f32x4*)(ksf + soff);
            f32x4 o2 = *(const f32x4*)(ksf + 4096 + soff);
            f32x4 o3 = *(const f32x4*)(vsf + soff);
            int d2 = j >> 2, base = (j & 3) * 4;
            float q0 = (a0 * oacc[d2][base + 0] + a1 * o1[0] + a2 * o2[0] + a3 * o3[0]) * inv;
            float q1 = (a0 * oacc[d2][base + 1] + a1 * o1[1] + a2 * o2[1] + a3 * o3[1]) * inv;
            float q2 = (a0 * oacc[d2][base + 2] + a1 * o1[2] + a2 * o2[2] + a3 * o3[2]) * inv;
            float q3 = (a0 * oacc[d2][base + 3] + a1 * o1[3] + a2 * o2[3] + a3 * o3[3]) * inv;
            uint2 pkv;
            pkv.x = cvtpk(q0, q1);
            pkv.y = cvtpk(q2, q3);
            *(uint2*)(ob + d2 * 32 + 8 * (j & 3) + 4 * hi) = pkv;
        }
    }
}

} // anonymous namespace

extern "C" void kernel_launch(void* const* d_in, const int* in_sizes, int n_in,
                              void* d_out, int out_size, void* d_ws, size_t ws_size,
                              hipStream_t stream)
{
    const float* x  = (const float*)d_in[0];
    const float* Wq = (const float*)d_in[1];
    const float* Wk = (const float*)d_in[2];
    const float* Wv = (const float*)d_in[3];
    const float* Wo = (const float*)d_in[4];

    ushort_t* xb  = (ushort_t*)d_ws;              // [4096][1024]        4M elems
    ushort_t* Wt  = xb  + 4194304;                // [3072][1024] (B^T)  3M elems
    ushort_t* Wot = Wt  + 3145728;                // [1024][1024] (B^T)  1M elems
    ushort_t* Qb  = Wot + 1048576;                // [32][2048][64]      4M elems
    ushort_t* Kb  = Qb  + 4194304;                // [32][2048][64]      4M elems
    ushort_t* Vtb = Kb  + 4194304;                // [32][64][2048]      4M elems
    ushort_t* Ob  = Vtb + 4194304;                // [4096][1024]        4M elems
    float*    tbl = (float*)(Ob + 4194304);       // [2048][32][2] fp32  512 KB

    conv_kernel<<<2048, 256, 0, stream>>>(x, xb);
    rope_table_kernel<<<256, 256, 0, stream>>>(tbl);
    tconv3_kernel<<<dim3(16, 1, 48), 256, 0, stream>>>(Wq, Wk, Wv, Wt);
    tconv_kernel<<<dim3(16, 16, 1), 256, 0, stream>>>(Wo, Wot, 1024, 1024);

    gemm_kernel<0><<<dim3(32, 24), 256, 0, stream>>>(xb, Wt, Qb, Kb, Vtb, nullptr, tbl, 1024);

    attn_kernel<<<1024, 512, 0, stream>>>(Qb, Kb, Vtb, Ob);

    gemm_kernel<1><<<dim3(32, 8), 256, 0, stream>>>(Ob, Wot, nullptr, nullptr, nullptr,
                                                    (float*)d_out, nullptr, 1024);
}